// Round 5
// baseline (3544.431 us; speedup 1.0000x reference)
//
#include <hip/hip_runtime.h>
#include <hip/hip_bf16.h>

#define B_ 16
#define N_ 577
#define C_ 1024
#define H_ 16
#define DH_ 64
#define M_ (B_*N_)          // 9232
#define KKEEP 144           // int(576 * 0.25)

// ---------------- helpers ----------------
__device__ __forceinline__ float b2f(unsigned short u){
  return __uint_as_float(((unsigned int)u) << 16);
}
__device__ __forceinline__ int wredi(int v){
  #pragma unroll
  for (int m=1;m<64;m<<=1) v += __shfl_xor(v, m, 64);
  return v;
}
__device__ __forceinline__ float wredmaxf(float v){
  #pragma unroll
  for (int m=1;m<64;m<<=1) v = fmaxf(v, __shfl_xor(v, m, 64));
  return v;
}
__device__ __forceinline__ float wredsumf(float v){
  #pragma unroll
  for (int m=1;m<64;m<<=1) v += __shfl_xor(v, m, 64);
  return v;
}
__device__ __forceinline__ unsigned sortkey(float f){
  unsigned i = __float_as_uint(f);
  return (i & 0x80000000u) ? ~i : (i | 0x80000000u);
}

// ---------------- kernel 1: QKV GEMM (fp32 compute) -> bf16 q/k/v scatter ----------------
__global__ __launch_bounds__(256) void gemm_qkv(
    const float* __restrict__ X, const float* __restrict__ W,
    __hip_bfloat16* __restrict__ qb, __hip_bfloat16* __restrict__ kb,
    __hip_bfloat16* __restrict__ vb)
{
  __shared__ float Xs[128][17];
  __shared__ float Ws[128][17];
  const int tid = threadIdx.x;
  const int tx = tid & 15, ty = tid >> 4;
  const int bm = blockIdx.x * 128, bn = blockIdx.y * 128;
  float acc[8][8];
  #pragma unroll
  for (int i=0;i<8;++i)
    #pragma unroll
    for (int j=0;j<8;++j) acc[i][j]=0.f;

  for (int k0=0; k0<1024; k0+=16){
    __syncthreads();
    #pragma unroll
    for (int p=0;p<2;++p){
      int f = tid + p*256;          // 0..511 -> 128 rows x 4 float4
      int row = f >> 2, cg = f & 3;
      int m = bm + row;
      float4 xv = make_float4(0.f,0.f,0.f,0.f);
      if (m < M_) xv = *(const float4*)(X + (size_t)m*1024 + k0 + cg*4);
      Xs[row][cg*4+0]=xv.x; Xs[row][cg*4+1]=xv.y; Xs[row][cg*4+2]=xv.z; Xs[row][cg*4+3]=xv.w;
      float4 wv = *(const float4*)(W + (size_t)(bn+row)*1024 + k0 + cg*4);
      Ws[row][cg*4+0]=wv.x; Ws[row][cg*4+1]=wv.y; Ws[row][cg*4+2]=wv.z; Ws[row][cg*4+3]=wv.w;
    }
    __syncthreads();
    #pragma unroll
    for (int kk=0; kk<16; ++kk){
      float a[8], b2[8];
      #pragma unroll
      for (int i=0;i<8;++i) a[i] = Xs[ty*8+i][kk];
      #pragma unroll
      for (int j=0;j<8;++j) b2[j] = Ws[tx*8+j][kk];
      #pragma unroll
      for (int i=0;i<8;++i)
        #pragma unroll
        for (int j=0;j<8;++j) acc[i][j] = fmaf(a[i], b2[j], acc[i][j]);
    }
  }
  #pragma unroll
  for (int i=0;i<8;++i){
    int m = bm + ty*8 + i;
    if (m >= M_) continue;
    int b = m / N_, n = m - b*N_;
    #pragma unroll
    for (int j=0;j<8;++j){
      int c = bn + tx*8 + j;
      int three = c >> 10, hh = (c >> 6) & 15, dd = c & 63;
      size_t off = ((size_t)(b*H_ + hh)*N_ + n)*DH_ + dd;
      __hip_bfloat16 val = __float2bfloat16(acc[i][j]);
      if (three == 0)      qb[off] = val;
      else if (three == 1) kb[off] = val;
      else                 vb[off] = val;
    }
  }
}

// ---------------- kernel 2: fused attention (QK^T, UCB top-k, softmax, PV) ----------------
__global__ __launch_bounds__(256) void attn_kernel(
    const __hip_bfloat16* __restrict__ qw, const __hip_bfloat16* __restrict__ kw,
    const __hip_bfloat16* __restrict__ vw,
    const float* __restrict__ ucb, const int* __restrict__ counter_p,
    __hip_bfloat16* __restrict__ ctx, int* __restrict__ delta)
{
  __shared__ float shmem[9232];      // QK phase: kt[128][69]; PV phase: P[16][577]
  __shared__ float qrow[16][64];
  __shared__ float expl_s[N_];
  __shared__ int   cnt_s[N_];

  const int tid = threadIdx.x;
  const int lane = tid & 63, wave = tid >> 6;
  const int blk = blockIdx.x;
  const int bh = blk / 37, tileq = blk % 37;
  const int h = bh & 15;
  const int row0 = tileq * 16;

  const float logc = logf((float)(*counter_p) + 1.0f);
  for (int k2=tid; k2<N_; k2+=256){
    cnt_s[k2] = 0;
    expl_s[k2] = (k2==0) ? 0.f : sqrtf(logc / (ucb[h*N_ + k2] + 1e-6f));
  }
  const unsigned short* qsrc = (const unsigned short*)qw;
  for (int idx=tid; idx<16*64; idx+=256){
    int r = idx >> 6, d = idx & 63;
    int n = row0 + r;
    qrow[r][d] = (n < N_) ? b2f(qsrc[((size_t)bh*N_ + n)*DH_ + d]) : 0.f;
  }

  float acc[4][10];
  #pragma unroll
  for (int r=0;r<4;++r)
    #pragma unroll
    for (int s=0;s<10;++s) acc[r][s]=0.f;

  const unsigned short* kbb = (const unsigned short*)kw + (size_t)bh*N_*DH_;
  for (int t=0;t<5;++t){
    __syncthreads();
    const int k0 = t*128;
    const int row = tid >> 1, d0 = (tid & 1)*32;
    const int n = k0 + row;
    float tmp[32];
    if (n < N_){
      const unsigned short* src = kbb + (size_t)n*DH_ + d0;
      #pragma unroll
      for (int g=0; g<4; ++g){
        uint4 u = *(const uint4*)(src + g*8);
        tmp[g*8+0]=b2f((unsigned short)(u.x&0xFFFF)); tmp[g*8+1]=b2f((unsigned short)(u.x>>16));
        tmp[g*8+2]=b2f((unsigned short)(u.y&0xFFFF)); tmp[g*8+3]=b2f((unsigned short)(u.y>>16));
        tmp[g*8+4]=b2f((unsigned short)(u.z&0xFFFF)); tmp[g*8+5]=b2f((unsigned short)(u.z>>16));
        tmp[g*8+6]=b2f((unsigned short)(u.w&0xFFFF)); tmp[g*8+7]=b2f((unsigned short)(u.w>>16));
      }
    } else {
      #pragma unroll
      for (int g=0; g<32; ++g) tmp[g] = 0.f;
    }
    #pragma unroll
    for (int g=0; g<32; ++g) shmem[row*69 + d0 + g] = tmp[g];
    __syncthreads();
    #pragma unroll 2
    for (int d=0; d<64; ++d){
      float kv0 = shmem[lane*69 + d];
      float kv1 = shmem[(64+lane)*69 + d];
      #pragma unroll
      for (int r=0;r<4;++r){
        float qv = qrow[wave*4+r][d];
        acc[r][2*t]   = fmaf(qv, kv0, acc[r][2*t]);
        acc[r][2*t+1] = fmaf(qv, kv1, acc[r][2*t+1]);
      }
    }
  }
  __syncthreads();   // QK done; shmem becomes P storage

  #pragma unroll
  for (int r=0;r<4;++r){
    const int lrow = wave*4 + r;
    const int n = row0 + lrow;
    const bool rv = (n < N_);
    float sc[10]; unsigned u[10];
    #pragma unroll
    for (int s=0;s<10;++s) sc[s] = acc[r][s]*0.125f;    // Dh^-0.5
    #pragma unroll
    for (int s=0;s<10;++s){
      int k = s*64 + lane;
      bool vt = (k >= 1) && (k < N_);
      float uv = sc[s] + (k < N_ ? expl_s[k] : 0.f);
      u[s] = vt ? sortkey(uv) : 0u;
    }
    // radix-select threshold T = max value with count(u>=T) >= KKEEP
    unsigned T = 0u;
    for (int bit=31; bit>=0; --bit){
      unsigned cand = T | (1u << bit);
      int c = 0;
      #pragma unroll
      for (int s=0;s<10;++s) c += (u[s] >= cand) ? 1 : 0;
      c = wredi(c);
      if (c >= KKEEP) T = cand;
    }
    int cgt = 0;
    #pragma unroll
    for (int s=0;s<10;++s) cgt += (u[s] > T) ? 1 : 0;
    cgt = wredi(cgt);
    const int rem = KKEEP - cgt;                        // # of ==T to keep, lowest index first
    unsigned long long em[10];
    #pragma unroll
    for (int s=0;s<10;++s) em[s] = __ballot(u[s] == T);
    const unsigned long long below = lane ? (~0ull >> (64 - lane)) : 0ull;
    bool keep[10];
    int pref = 0;
    #pragma unroll
    for (int s=0;s<10;++s){
      int k = s*64 + lane;
      bool kp2 = false;
      if (k == 0) kp2 = true;
      else if (k < N_){
        if (u[s] > T) kp2 = true;
        else if (u[s] == T) kp2 = (pref + __popcll(em[s] & below)) < rem;
      }
      keep[s] = kp2;
      pref += __popcll(em[s]);
    }
    // masked softmax
    float mx = -3.4e38f;
    #pragma unroll
    for (int s=0;s<10;++s) if (keep[s]) mx = fmaxf(mx, sc[s]);
    mx = wredmaxf(mx);
    float p[10]; float den = 0.f;
    #pragma unroll
    for (int s=0;s<10;++s){ p[s] = keep[s] ? __expf(sc[s]-mx) : 0.f; den += p[s]; }
    den = wredsumf(den);
    const float inv = 1.0f/den;
    #pragma unroll
    for (int s=0;s<10;++s){
      int k = s*64 + lane;
      if (k < N_) shmem[lrow*N_ + k] = p[s]*inv;
      if (rv && keep[s]) atomicAdd(&cnt_s[k < N_ ? k : 0], 1);
    }
  }

  // PV: each wave handles its own 4 rows
  float o0=0.f,o1=0.f,o2=0.f,o3=0.f;
  const unsigned short* vbb = (const unsigned short*)vw + (size_t)bh*N_*DH_;
  const float* pr = &shmem[(wave*4)*N_];
  #pragma unroll 4
  for (int k=0;k<N_;++k){
    float vv = b2f(vbb[(size_t)k*DH_ + lane]);
    o0 = fmaf(pr[0*N_ + k], vv, o0);
    o1 = fmaf(pr[1*N_ + k], vv, o1);
    o2 = fmaf(pr[2*N_ + k], vv, o2);
    o3 = fmaf(pr[3*N_ + k], vv, o3);
  }
  {
    int n0 = row0 + wave*4;
    if (n0+0 < N_) ctx[((size_t)bh*N_ + n0+0)*DH_ + lane] = __float2bfloat16(o0);
    if (n0+1 < N_) ctx[((size_t)bh*N_ + n0+1)*DH_ + lane] = __float2bfloat16(o1);
    if (n0+2 < N_) ctx[((size_t)bh*N_ + n0+2)*DH_ + lane] = __float2bfloat16(o2);
    if (n0+3 < N_) ctx[((size_t)bh*N_ + n0+3)*DH_ + lane] = __float2bfloat16(o3);
  }
  __syncthreads();
  for (int k2=tid; k2<N_; k2+=256){
    int c2 = cnt_s[k2];
    if (c2) atomicAdd(&delta[h*N_ + k2], c2);
  }
}

// ---------------- kernel 3: output projection -> FP32 out ----------------
__global__ __launch_bounds__(256) void gemm_proj(
    const __hip_bfloat16* __restrict__ Abf, const float* __restrict__ W,
    const float* __restrict__ bias, float* __restrict__ out)
{
  __shared__ float As[128][17];
  __shared__ float Ws[128][17];
  const int tid = threadIdx.x;
  const int tx = tid & 15, ty = tid >> 4;
  const int bm = blockIdx.x * 128, bn = blockIdx.y * 128;
  float acc[8][8];
  #pragma unroll
  for (int i=0;i<8;++i)
    #pragma unroll
    for (int j=0;j<8;++j) acc[i][j]=0.f;

  const unsigned short* A16 = (const unsigned short*)Abf;
  for (int k0=0; k0<1024; k0+=16){
    __syncthreads();
    #pragma unroll
    for (int p=0;p<2;++p){
      int f = tid + p*256;
      int row = f >> 2, cg = f & 3;
      int mm = bm + row;
      int c  = k0 + cg*4;                  // 4 cols, same h (c%64 multiple of 4)
      float4 av = make_float4(0.f,0.f,0.f,0.f);
      if (mm < M_){
        int b = mm / N_, n = mm - b*N_;
        int hh = c >> 6, dd = c & 63;
        const unsigned short* src = A16 + (((size_t)(b*H_ + hh))*N_ + n)*DH_ + dd;
        ushort4 uv = *(const ushort4*)src;
        av.x = b2f(uv.x); av.y = b2f(uv.y); av.z = b2f(uv.z); av.w = b2f(uv.w);
      }
      As[row][cg*4+0]=av.x; As[row][cg*4+1]=av.y; As[row][cg*4+2]=av.z; As[row][cg*4+3]=av.w;
      float4 wv = *(const float4*)(W + (size_t)(bn+row)*1024 + k0 + cg*4);
      Ws[row][cg*4+0]=wv.x; Ws[row][cg*4+1]=wv.y; Ws[row][cg*4+2]=wv.z; Ws[row][cg*4+3]=wv.w;
    }
    __syncthreads();
    #pragma unroll
    for (int kk=0; kk<16; ++kk){
      float a[8], b2r[8];
      #pragma unroll
      for (int i=0;i<8;++i) a[i] = As[ty*8+i][kk];
      #pragma unroll
      for (int j=0;j<8;++j) b2r[j] = Ws[tx*8+j][kk];
      #pragma unroll
      for (int i=0;i<8;++i)
        #pragma unroll
        for (int j=0;j<8;++j) acc[i][j] = fmaf(a[i], b2r[j], acc[i][j]);
    }
  }
  float bv[8];
  #pragma unroll
  for (int j=0;j<8;++j) bv[j] = bias[bn + tx*8 + j];
  #pragma unroll
  for (int i=0;i<8;++i){
    int m = bm + ty*8 + i;
    if (m >= M_) continue;
    #pragma unroll
    for (int j=0;j<8;++j){
      int c = bn + tx*8 + j;
      out[(size_t)m*1024 + c] = acc[i][j] + bv[j];
    }
  }
}

// ---------------- kernel 4: score_delta int -> FP32 tail of d_out ----------------
__global__ void delta_to_f32(const int* __restrict__ delta, float* __restrict__ outd){
  int i = blockIdx.x*256 + threadIdx.x;
  if (i < H_*N_) outd[i] = (float)delta[i];
}

extern "C" void kernel_launch(void* const* d_in, const int* in_sizes, int n_in,
                              void* d_out, int out_size, void* d_ws, size_t ws_size,
                              hipStream_t stream) {
  const float* x      = (const float*)d_in[0];
  const float* qkv_w  = (const float*)d_in[1];
  const float* proj_w = (const float*)d_in[2];
  const float* proj_b = (const float*)d_in[3];
  const float* ucb    = (const float*)d_in[4];
  const int*   counter= (const int*)d_in[5];

  // d_out is FP32: [out (9,453,568 f32) | score_delta (9,232 f32)]
  float* outO = (float*)d_out;
  float* outD = outO + ((size_t)out_size - (size_t)H_*N_);   // end-aligned via runtime out_size

  // workspace: 3 * 9,453,568 bf16 + 9232 int  =  ~54.1 MiB total
  __hip_bfloat16* qb = (__hip_bfloat16*)d_ws;        // [bh][n][64]; doubles as ctx
  __hip_bfloat16* kb = qb + (size_t)M_*C_;
  __hip_bfloat16* vb = kb + (size_t)M_*C_;
  int*         delta = (int*)(vb + (size_t)M_*C_);

  hipMemsetAsync(delta, 0, (size_t)H_*N_*sizeof(int), stream);
  gemm_qkv<<<dim3(73,24), 256, 0, stream>>>(x, qkv_w, qb, kb, vb);
  attn_kernel<<<dim3(256*37), 256, 0, stream>>>(qb, kb, vb, ucb, counter, qb /*ctx alias*/, delta);
  gemm_proj<<<dim3(73,8), 256, 0, stream>>>(qb, proj_w, proj_b, outO);
  delta_to_f32<<<dim3(37), 256, 0, stream>>>(delta, outD);
}

// Round 7
// 1232.971 us; speedup vs baseline: 2.8747x; 2.8747x over previous
//
#include <hip/hip_runtime.h>
#include <hip/hip_bf16.h>

#define B_ 16
#define N_ 577
#define C_ 1024
#define H_ 16
#define DH_ 64
#define M_ (B_*N_)          // 9232
#define KKEEP 144           // int(576 * 0.25)

typedef __attribute__((ext_vector_type(8))) short bf16x8;
typedef __attribute__((ext_vector_type(4))) float f32x4;

// ---------------- helpers ----------------
__device__ __forceinline__ float b2f(unsigned short u){ return __uint_as_float(((unsigned int)u) << 16); }
__device__ __forceinline__ float lo16(unsigned int u){ return __uint_as_float(u << 16); }
__device__ __forceinline__ float hi16(unsigned int u){ return __uint_as_float(u & 0xffff0000u); }
__device__ __forceinline__ unsigned short f2bu(float f){
  __hip_bfloat16 h = __float2bfloat16(f);
  return *(unsigned short*)&h;
}
__device__ __forceinline__ int wredi(int v){
  #pragma unroll
  for (int m=1;m<64;m<<=1) v += __shfl_xor(v, m, 64);
  return v;
}
__device__ __forceinline__ float wredmaxf(float v){
  #pragma unroll
  for (int m=1;m<64;m<<=1) v = fmaxf(v, __shfl_xor(v, m, 64));
  return v;
}
__device__ __forceinline__ float wredsumf(float v){
  #pragma unroll
  for (int m=1;m<64;m<<=1) v += __shfl_xor(v, m, 64);
  return v;
}
__device__ __forceinline__ unsigned sortkey(float f){
  unsigned i = __float_as_uint(f);
  return (i & 0x80000000u) ? ~i : (i | 0x80000000u);
}

// ---------------- kernel 1: QKV GEMM via MFMA (bf16 in, fp32 acc) ----------------
__global__ __launch_bounds__(256) void gemm_qkv_mfma(
    const float* __restrict__ X, const float* __restrict__ W,
    unsigned short* __restrict__ qb, unsigned short* __restrict__ kb,
    unsigned short* __restrict__ vb)
{
  __shared__ unsigned short As[128][40];
  __shared__ unsigned short Bs[128][40];
  const int tid = threadIdx.x;
  const int lane = tid & 63, wave = tid >> 6;
  const int wm = wave >> 1, wn = wave & 1;
  const int lr = lane & 15, kh = lane >> 4;
  const int bm = blockIdx.x*128, bn = blockIdx.y*128;
  const int srow = tid >> 1, shalf = tid & 1;

  f32x4 acc[4][4];
  #pragma unroll
  for (int i=0;i<4;++i)
    #pragma unroll
    for (int j=0;j<4;++j) acc[i][j] = (f32x4){0.f,0.f,0.f,0.f};

  for (int k0=0; k0<1024; k0+=32){
    __syncthreads();
    {
      unsigned short t16[16];
      int m = bm + srow;
      if (m < M_){
        const float4* s = (const float4*)(X + (size_t)m*1024 + k0 + shalf*16);
        #pragma unroll
        for (int g=0; g<4; ++g){
          float4 v = s[g];
          t16[g*4+0]=f2bu(v.x); t16[g*4+1]=f2bu(v.y); t16[g*4+2]=f2bu(v.z); t16[g*4+3]=f2bu(v.w);
        }
      } else {
        #pragma unroll
        for (int g=0; g<16; ++g) t16[g]=0;
      }
      *(uint4*)&As[srow][shalf*16]   = *(uint4*)&t16[0];
      *(uint4*)&As[srow][shalf*16+8] = *(uint4*)&t16[8];

      const float4* sw = (const float4*)(W + (size_t)(bn+srow)*1024 + k0 + shalf*16);
      #pragma unroll
      for (int g=0; g<4; ++g){
        float4 v = sw[g];
        t16[g*4+0]=f2bu(v.x); t16[g*4+1]=f2bu(v.y); t16[g*4+2]=f2bu(v.z); t16[g*4+3]=f2bu(v.w);
      }
      *(uint4*)&Bs[srow][shalf*16]   = *(uint4*)&t16[0];
      *(uint4*)&Bs[srow][shalf*16+8] = *(uint4*)&t16[8];
    }
    __syncthreads();
    bf16x8 af[4], bfr[4];
    #pragma unroll
    for (int f=0; f<4; ++f){
      af[f]  = *(const bf16x8*)&As[wm*64 + f*16 + lr][kh*8];
      bfr[f] = *(const bf16x8*)&Bs[wn*64 + f*16 + lr][kh*8];
    }
    #pragma unroll
    for (int fm=0; fm<4; ++fm)
      #pragma unroll
      for (int fn=0; fn<4; ++fn)
        acc[fm][fn] = __builtin_amdgcn_mfma_f32_16x16x32_bf16(af[fm], bfr[fn], acc[fm][fn], 0,0,0);
  }
  #pragma unroll
  for (int fm=0; fm<4; ++fm){
    #pragma unroll
    for (int j=0; j<4; ++j){
      int m = bm + wm*64 + fm*16 + kh*4 + j;
      if (m >= M_) continue;
      int b = m / N_, n = m - b*N_;
      #pragma unroll
      for (int fn=0; fn<4; ++fn){
        int c = bn + wn*64 + fn*16 + lr;
        int three = c >> 10, hh = (c >> 6) & 15, dd = c & 63;
        size_t off = ((size_t)(b*H_ + hh)*N_ + n)*DH_ + dd;
        unsigned short val = f2bu(acc[fm][fn][j]);
        if (three == 0)      qb[off] = val;
        else if (three == 1) kb[off] = val;
        else                 vb[off] = val;
      }
    }
  }
}

// ---------------- kernel 2: fused attention ----------------
__global__ __launch_bounds__(256,5) void attn_kernel(
    const unsigned short* __restrict__ qw, const unsigned short* __restrict__ kw,
    const unsigned short* __restrict__ vw,
    const float* __restrict__ ucb, const int* __restrict__ counter_p,
    unsigned short* __restrict__ ctx, int* __restrict__ delta)
{
  __shared__ __align__(16) char smem_u[20480];                 // kt: 128*40*4=20480B | pus: 18688B
  unsigned int (*kt)[40] = (unsigned int (*)[40])smem_u;       // 128 keys x 32 d-pairs (+8 pad)
  unsigned short (*pus)[584] = (unsigned short (*)[584])smem_u;// 16 rows x P bf16
  __shared__ float qrow[16][64];
  __shared__ float expl_s[584];
  __shared__ int   cnt_s[584];

  const int tid = threadIdx.x;
  const int lane = tid & 63, wave = tid >> 6;
  const int blk = blockIdx.x;
  const int bh = blk / 37, tileq = blk % 37;
  const int h = bh & 15;
  const int row0 = tileq * 16;

  const float logc = logf((float)(*counter_p) + 1.0f);
  for (int k2=tid; k2<N_; k2+=256){
    cnt_s[k2] = 0;
    expl_s[k2] = (k2==0) ? 0.f : sqrtf(logc / (ucb[h*N_ + k2] + 1e-6f));
  }
  if (tid < 128){
    int r = tid >> 3, part = tid & 7;
    int n = row0 + r;
    float q8[8];
    if (n < N_){
      uint4 u = *(const uint4*)(qw + ((size_t)bh*N_ + n)*DH_ + part*8);
      q8[0]=lo16(u.x); q8[1]=hi16(u.x); q8[2]=lo16(u.y); q8[3]=hi16(u.y);
      q8[4]=lo16(u.z); q8[5]=hi16(u.z); q8[6]=lo16(u.w); q8[7]=hi16(u.w);
    } else {
      #pragma unroll
      for (int g=0; g<8; ++g) q8[g]=0.f;
    }
    *(float4*)&qrow[r][part*8]   = make_float4(q8[0],q8[1],q8[2],q8[3]);
    *(float4*)&qrow[r][part*8+4] = make_float4(q8[4],q8[5],q8[6],q8[7]);
  }

  float acc[4][10];
  #pragma unroll
  for (int r=0;r<4;++r)
    #pragma unroll
    for (int s=0;s<10;++s) acc[r][s]=0.f;

  const unsigned short* kbb = kw + (size_t)bh*N_*DH_;
  for (int t=0;t<5;++t){
    __syncthreads();
    {
      // FIX (r6 bug): stage the FULL 32 bf16 per thread (4 x uint4)
      const int key = tid >> 1, halfk = tid & 1;
      int n = t*128 + key;
      uint4 a0={0,0,0,0}, a1={0,0,0,0}, a2={0,0,0,0}, a3={0,0,0,0};
      if (n < N_){
        const uint4* s = (const uint4*)(kbb + (size_t)n*DH_ + halfk*32);
        a0 = s[0]; a1 = s[1]; a2 = s[2]; a3 = s[3];
      }
      *(uint4*)&kt[key][halfk*16]    = a0;
      *(uint4*)&kt[key][halfk*16+4]  = a1;
      *(uint4*)&kt[key][halfk*16+8]  = a2;
      *(uint4*)&kt[key][halfk*16+12] = a3;
    }
    __syncthreads();
    #pragma unroll
    for (int dg=0; dg<8; ++dg){
      uint4 ka = *(const uint4*)&kt[lane][dg*4];
      uint4 kc = *(const uint4*)&kt[64+lane][dg*4];
      float kfa[8], kfb[8];
      kfa[0]=lo16(ka.x); kfa[1]=hi16(ka.x); kfa[2]=lo16(ka.y); kfa[3]=hi16(ka.y);
      kfa[4]=lo16(ka.z); kfa[5]=hi16(ka.z); kfa[6]=lo16(ka.w); kfa[7]=hi16(ka.w);
      kfb[0]=lo16(kc.x); kfb[1]=hi16(kc.x); kfb[2]=lo16(kc.y); kfb[3]=hi16(kc.y);
      kfb[4]=lo16(kc.z); kfb[5]=hi16(kc.z); kfb[6]=lo16(kc.w); kfb[7]=hi16(kc.w);
      #pragma unroll
      for (int r=0;r<4;++r){
        float4 qa  = *(const float4*)&qrow[wave*4+r][dg*8];
        float4 qb4 = *(const float4*)&qrow[wave*4+r][dg*8+4];
        float q8[8] = {qa.x,qa.y,qa.z,qa.w,qb4.x,qb4.y,qb4.z,qb4.w};
        float s0 = acc[r][2*t], s1 = acc[r][2*t+1];
        #pragma unroll
        for (int d=0; d<8; ++d){
          s0 = fmaf(q8[d], kfa[d], s0);
          s1 = fmaf(q8[d], kfb[d], s1);
        }
        acc[r][2*t]=s0; acc[r][2*t+1]=s1;
      }
    }
  }
  __syncthreads();   // QK done; smem_u becomes P storage

  #pragma unroll
  for (int r=0;r<4;++r){
    const int lrow = wave*4 + r;
    const int n = row0 + lrow;
    const bool rv = (n < N_);
    float sc[10]; unsigned u[10];
    #pragma unroll
    for (int s=0;s<10;++s) sc[s] = acc[r][s]*0.125f;
    #pragma unroll
    for (int s=0;s<10;++s){
      int k = s*64 + lane;
      bool vt = (k >= 1) && (k < N_);
      float uv = sc[s] + (k < N_ ? expl_s[k] : 0.f);
      u[s] = vt ? sortkey(uv) : 0u;
    }
    unsigned T = 0u;
    for (int bit=31; bit>=0; --bit){
      unsigned cand = T | (1u << bit);
      int c = 0;
      #pragma unroll
      for (int s=0;s<10;++s) c += (u[s] >= cand) ? 1 : 0;
      c = wredi(c);
      if (c >= KKEEP) T = cand;
    }
    int cgt = 0;
    #pragma unroll
    for (int s=0;s<10;++s) cgt += (u[s] > T) ? 1 : 0;
    cgt = wredi(cgt);
    const int rem = KKEEP - cgt;
    unsigned long long em[10];
    #pragma unroll
    for (int s=0;s<10;++s) em[s] = __ballot(u[s] == T);
    const unsigned long long below = lane ? (~0ull >> (64 - lane)) : 0ull;
    bool keep[10];
    int pref = 0;
    #pragma unroll
    for (int s=0;s<10;++s){
      int k = s*64 + lane;
      bool kp2 = false;
      if (k == 0) kp2 = true;
      else if (k < N_){
        if (u[s] > T) kp2 = true;
        else if (u[s] == T) kp2 = (pref + __popcll(em[s] & below)) < rem;
      }
      keep[s] = kp2;
      pref += __popcll(em[s]);
    }
    float mx = -3.4e38f;
    #pragma unroll
    for (int s=0;s<10;++s) if (keep[s]) mx = fmaxf(mx, sc[s]);
    mx = wredmaxf(mx);
    float p[10]; float den = 0.f;
    #pragma unroll
    for (int s=0;s<10;++s){ p[s] = keep[s] ? __expf(sc[s]-mx) : 0.f; den += p[s]; }
    den = wredsumf(den);
    const float inv = 1.0f/den;
    #pragma unroll
    for (int s=0;s<10;++s){
      int k = s*64 + lane;
      if (k < N_) pus[lrow][k] = f2bu(p[s]*inv);
      if (rv && keep[s]) atomicAdd(&cnt_s[k < N_ ? k : 0], 1);
    }
  }

  // PV
  float o0=0.f,o1=0.f,o2=0.f,o3=0.f;
  const unsigned short* vbb = vw + (size_t)bh*N_*DH_;
  const int w4 = wave*4;
  #pragma unroll 2
  for (int kp=0; kp<288; ++kp){
    float v0 = b2f(vbb[(size_t)(2*kp)*DH_ + lane]);
    float v1 = b2f(vbb[(size_t)(2*kp+1)*DH_ + lane]);
    unsigned int p0 = *(const unsigned int*)&pus[w4+0][2*kp];
    unsigned int p1 = *(const unsigned int*)&pus[w4+1][2*kp];
    unsigned int p2 = *(const unsigned int*)&pus[w4+2][2*kp];
    unsigned int p3 = *(const unsigned int*)&pus[w4+3][2*kp];
    o0 = fmaf(lo16(p0), v0, fmaf(hi16(p0), v1, o0));
    o1 = fmaf(lo16(p1), v0, fmaf(hi16(p1), v1, o1));
    o2 = fmaf(lo16(p2), v0, fmaf(hi16(p2), v1, o2));
    o3 = fmaf(lo16(p3), v0, fmaf(hi16(p3), v1, o3));
  }
  {
    float v0 = b2f(vbb[(size_t)576*DH_ + lane]);
    o0 = fmaf(b2f(pus[w4+0][576]), v0, o0);
    o1 = fmaf(b2f(pus[w4+1][576]), v0, o1);
    o2 = fmaf(b2f(pus[w4+2][576]), v0, o2);
    o3 = fmaf(b2f(pus[w4+3][576]), v0, o3);
  }
  {
    int n0 = row0 + w4;
    if (n0+0 < N_) ctx[((size_t)bh*N_ + n0+0)*DH_ + lane] = f2bu(o0);
    if (n0+1 < N_) ctx[((size_t)bh*N_ + n0+1)*DH_ + lane] = f2bu(o1);
    if (n0+2 < N_) ctx[((size_t)bh*N_ + n0+2)*DH_ + lane] = f2bu(o2);
    if (n0+3 < N_) ctx[((size_t)bh*N_ + n0+3)*DH_ + lane] = f2bu(o3);
  }
  __syncthreads();
  for (int k2=tid; k2<N_; k2+=256){
    int c2 = cnt_s[k2];
    if (c2) atomicAdd(&delta[h*N_ + k2], c2);
  }
}

// ---------------- kernel 3: output projection via MFMA -> FP32 out ----------------
__global__ __launch_bounds__(256) void gemm_proj_mfma(
    const unsigned short* __restrict__ ctxp, const float* __restrict__ W,
    const float* __restrict__ bias, float* __restrict__ out)
{
  __shared__ unsigned short As[128][40];
  __shared__ unsigned short Bs[128][40];
  const int tid = threadIdx.x;
  const int lane = tid & 63, wave = tid >> 6;
  const int wm = wave >> 1, wn = wave & 1;
  const int lr = lane & 15, kh = lane >> 4;
  const int bm = blockIdx.x*128, bn = blockIdx.y*128;
  const int srow = tid >> 1, shalf = tid & 1;

  f32x4 acc[4][4];
  #pragma unroll
  for (int i=0;i<4;++i)
    #pragma unroll
    for (int j=0;j<4;++j) acc[i][j] = (f32x4){0.f,0.f,0.f,0.f};

  const int m_s = bm + srow;
  const int bb = m_s / N_, nn = m_s - bb*N_;

  for (int k0=0; k0<1024; k0+=32){
    __syncthreads();
    {
      uint4 a0 = {0,0,0,0}, a1 = {0,0,0,0};
      if (m_s < M_){
        int hh = k0 >> 6, dd = (k0 & 63) + shalf*16;
        const uint4* s = (const uint4*)(ctxp + ((size_t)(bb*H_ + hh)*N_ + nn)*DH_ + dd);
        a0 = s[0]; a1 = s[1];
      }
      *(uint4*)&As[srow][shalf*16]   = a0;
      *(uint4*)&As[srow][shalf*16+8] = a1;   // FIX (r6 bug): +8 ushorts, not +4
      unsigned short t16[16];
      const float4* sw = (const float4*)(W + (size_t)(bn+srow)*1024 + k0 + shalf*16);
      #pragma unroll
      for (int g=0; g<4; ++g){
        float4 v = sw[g];
        t16[g*4+0]=f2bu(v.x); t16[g*4+1]=f2bu(v.y); t16[g*4+2]=f2bu(v.z); t16[g*4+3]=f2bu(v.w);
      }
      *(uint4*)&Bs[srow][shalf*16]   = *(uint4*)&t16[0];
      *(uint4*)&Bs[srow][shalf*16+8] = *(uint4*)&t16[8];
    }
    __syncthreads();
    bf16x8 af[4], bfr[4];
    #pragma unroll
    for (int f=0; f<4; ++f){
      af[f]  = *(const bf16x8*)&As[wm*64 + f*16 + lr][kh*8];
      bfr[f] = *(const bf16x8*)&Bs[wn*64 + f*16 + lr][kh*8];
    }
    #pragma unroll
    for (int fm=0; fm<4; ++fm)
      #pragma unroll
      for (int fn=0; fn<4; ++fn)
        acc[fm][fn] = __builtin_amdgcn_mfma_f32_16x16x32_bf16(af[fm], bfr[fn], acc[fm][fn], 0,0,0);
  }
  float bv[4];
  #pragma unroll
  for (int fn=0; fn<4; ++fn) bv[fn] = bias[bn + wn*64 + fn*16 + lr];
  #pragma unroll
  for (int fm=0; fm<4; ++fm){
    #pragma unroll
    for (int j=0; j<4; ++j){
      int m = bm + wm*64 + fm*16 + kh*4 + j;
      if (m >= M_) continue;
      #pragma unroll
      for (int fn=0; fn<4; ++fn){
        int c = bn + wn*64 + fn*16 + lr;
        out[(size_t)m*1024 + c] = acc[fm][fn][j] + bv[fn];
      }
    }
  }
}

// ---------------- kernel 4: score_delta int -> FP32 tail of d_out ----------------
__global__ void delta_to_f32(const int* __restrict__ delta, float* __restrict__ outd){
  int i = blockIdx.x*256 + threadIdx.x;
  if (i < H_*N_) outd[i] = (float)delta[i];
}

extern "C" void kernel_launch(void* const* d_in, const int* in_sizes, int n_in,
                              void* d_out, int out_size, void* d_ws, size_t ws_size,
                              hipStream_t stream) {
  const float* x      = (const float*)d_in[0];
  const float* qkv_w  = (const float*)d_in[1];
  const float* proj_w = (const float*)d_in[2];
  const float* proj_b = (const float*)d_in[3];
  const float* ucb    = (const float*)d_in[4];
  const int*   counter= (const int*)d_in[5];

  float* outO = (float*)d_out;
  float* outD = outO + ((size_t)out_size - (size_t)H_*N_);

  unsigned short* qb = (unsigned short*)d_ws;   // [bh][n][64]; doubles as ctx
  unsigned short* kb = qb + (size_t)M_*C_;
  unsigned short* vb = kb + (size_t)M_*C_;
  int*         delta = (int*)(vb + (size_t)M_*C_);

  hipMemsetAsync(delta, 0, (size_t)H_*N_*sizeof(int), stream);
  gemm_qkv_mfma<<<dim3(73,24), 256, 0, stream>>>(x, qkv_w, qb, kb, vb);
  attn_kernel<<<dim3(256*37), 256, 0, stream>>>(qb, kb, vb, ucb, counter, qb /*ctx alias*/, delta);
  gemm_proj_mfma<<<dim3(73,8), 256, 0, stream>>>(qb, proj_w, proj_b, outO);
  delta_to_f32<<<dim3(37), 256, 0, stream>>>(delta, outD);
}

// Round 8
// 799.557 us; speedup vs baseline: 4.4330x; 1.5421x over previous
//
#include <hip/hip_runtime.h>
#include <hip/hip_bf16.h>

#define B_ 16
#define N_ 577
#define C_ 1024
#define H_ 16
#define DH_ 64
#define M_ (B_*N_)          // 9232
#define KKEEP 144           // int(576 * 0.25)

typedef __attribute__((ext_vector_type(8))) short bf16x8;
typedef __attribute__((ext_vector_type(4))) float f32x4;

// ---------------- helpers ----------------
__device__ __forceinline__ float b2f(unsigned short u){ return __uint_as_float(((unsigned int)u) << 16); }
__device__ __forceinline__ float lo16(unsigned int u){ return __uint_as_float(u << 16); }
__device__ __forceinline__ float hi16(unsigned int u){ return __uint_as_float(u & 0xffff0000u); }
__device__ __forceinline__ unsigned short f2bu(float f){
  __hip_bfloat16 h = __float2bfloat16(f);
  return *(unsigned short*)&h;
}
__device__ __forceinline__ float wredmaxf(float v){
  #pragma unroll
  for (int m=1;m<64;m<<=1) v = fmaxf(v, __shfl_xor(v, m, 64));
  return v;
}
__device__ __forceinline__ float wredsumf(float v){
  #pragma unroll
  for (int m=1;m<64;m<<=1) v += __shfl_xor(v, m, 64);
  return v;
}
__device__ __forceinline__ unsigned sortkey(float f){
  unsigned i = __float_as_uint(f);
  return (i & 0x80000000u) ? ~i : (i | 0x80000000u);
}

// ---------------- kernel 1: QKV GEMM via MFMA (unchanged from r7) ----------------
__global__ __launch_bounds__(256) void gemm_qkv_mfma(
    const float* __restrict__ X, const float* __restrict__ W,
    unsigned short* __restrict__ qb, unsigned short* __restrict__ kb,
    unsigned short* __restrict__ vb)
{
  __shared__ unsigned short As[128][40];
  __shared__ unsigned short Bs[128][40];
  const int tid = threadIdx.x;
  const int lane = tid & 63, wave = tid >> 6;
  const int wm = wave >> 1, wn = wave & 1;
  const int lr = lane & 15, kh = lane >> 4;
  const int bm = blockIdx.x*128, bn = blockIdx.y*128;
  const int srow = tid >> 1, shalf = tid & 1;

  f32x4 acc[4][4];
  #pragma unroll
  for (int i=0;i<4;++i)
    #pragma unroll
    for (int j=0;j<4;++j) acc[i][j] = (f32x4){0.f,0.f,0.f,0.f};

  for (int k0=0; k0<1024; k0+=32){
    __syncthreads();
    {
      unsigned short t16[16];
      int m = bm + srow;
      if (m < M_){
        const float4* s = (const float4*)(X + (size_t)m*1024 + k0 + shalf*16);
        #pragma unroll
        for (int g=0; g<4; ++g){
          float4 v = s[g];
          t16[g*4+0]=f2bu(v.x); t16[g*4+1]=f2bu(v.y); t16[g*4+2]=f2bu(v.z); t16[g*4+3]=f2bu(v.w);
        }
      } else {
        #pragma unroll
        for (int g=0; g<16; ++g) t16[g]=0;
      }
      *(uint4*)&As[srow][shalf*16]   = *(uint4*)&t16[0];
      *(uint4*)&As[srow][shalf*16+8] = *(uint4*)&t16[8];

      const float4* sw = (const float4*)(W + (size_t)(bn+srow)*1024 + k0 + shalf*16);
      #pragma unroll
      for (int g=0; g<4; ++g){
        float4 v = sw[g];
        t16[g*4+0]=f2bu(v.x); t16[g*4+1]=f2bu(v.y); t16[g*4+2]=f2bu(v.z); t16[g*4+3]=f2bu(v.w);
      }
      *(uint4*)&Bs[srow][shalf*16]   = *(uint4*)&t16[0];
      *(uint4*)&Bs[srow][shalf*16+8] = *(uint4*)&t16[8];
    }
    __syncthreads();
    bf16x8 af[4], bfr[4];
    #pragma unroll
    for (int f=0; f<4; ++f){
      af[f]  = *(const bf16x8*)&As[wm*64 + f*16 + lr][kh*8];
      bfr[f] = *(const bf16x8*)&Bs[wn*64 + f*16 + lr][kh*8];
    }
    #pragma unroll
    for (int fm=0; fm<4; ++fm)
      #pragma unroll
      for (int fn=0; fn<4; ++fn)
        acc[fm][fn] = __builtin_amdgcn_mfma_f32_16x16x32_bf16(af[fm], bfr[fn], acc[fm][fn], 0,0,0);
  }
  #pragma unroll
  for (int fm=0; fm<4; ++fm){
    #pragma unroll
    for (int j=0; j<4; ++j){
      int m = bm + wm*64 + fm*16 + kh*4 + j;
      if (m >= M_) continue;
      int b = m / N_, n = m - b*N_;
      #pragma unroll
      for (int fn=0; fn<4; ++fn){
        int c = bn + wn*64 + fn*16 + lr;
        int three = c >> 10, hh = (c >> 6) & 15, dd = c & 63;
        size_t off = ((size_t)(b*H_ + hh)*N_ + n)*DH_ + dd;
        unsigned short val = f2bu(acc[fm][fn][j]);
        if (three == 0)      qb[off] = val;
        else if (three == 1) kb[off] = val;
        else                 vb[off] = val;
      }
    }
  }
}

// ---------------- kernel 2: fused attention (QK via MFMA, ballot radix) ----------------
__global__ __launch_bounds__(256,5) void attn_kernel(
    const unsigned short* __restrict__ qw, const unsigned short* __restrict__ kw,
    const unsigned short* __restrict__ vw,
    const float* __restrict__ ucb, const int* __restrict__ counter_p,
    unsigned short* __restrict__ ctx, int* __restrict__ delta)
{
  __shared__ __align__(16) float S[16][320];       // 20480B; P (bf16) aliases after QK
  __shared__ float expl_s[584];
  __shared__ int   cnt_s[584];
  unsigned short (*pus)[584] = (unsigned short (*)[584])&S[0][0];   // 18688B <= 20480B

  const int tid = threadIdx.x;
  const int lane = tid & 63, wave = tid >> 6;
  const int lr = lane & 15, kh = lane >> 4;
  const int blk = blockIdx.x;
  const int bh = blk / 37, tileq = blk % 37;
  const int h = bh & 15;
  const int row0 = tileq * 16;

  const float logc = logf((float)(*counter_p) + 1.0f);
  for (int k2=tid; k2<N_; k2+=256){
    cnt_s[k2] = 0;
    expl_s[k2] = (k2==0) ? 0.f : sqrtf(logc / (ucb[h*N_ + k2] + 1e-6f));
  }

  // ---- QK^T via MFMA: S[q][key], A=Q[16][64], B=K[key][64], both [row][k] bf16 ----
  const unsigned short* qbb = qw + (size_t)bh*N_*DH_;
  const unsigned short* kbb = kw + (size_t)bh*N_*DH_;
  bf16x8 aq0 = {0,0,0,0,0,0,0,0}, aq1 = {0,0,0,0,0,0,0,0};
  {
    int qr = row0 + lr;
    if (qr < N_){
      aq0 = *(const bf16x8*)(qbb + (size_t)qr*DH_ + kh*8);
      aq1 = *(const bf16x8*)(qbb + (size_t)qr*DH_ + 32 + kh*8);
    }
  }

  float acc[4][10];
  #pragma unroll
  for (int r=0;r<4;++r)
    #pragma unroll
    for (int s=0;s<10;++s) acc[r][s]=0.f;

  #pragma unroll
  for (int half=0; half<2; ++half){
    const int t0 = half ? 20 : 0, t1 = half ? 37 : 20, keyoff = half*320;
    for (int tile = t0 + wave; tile < t1; tile += 4){
      int keyr = tile*16 + lr;
      bf16x8 b0 = {0,0,0,0,0,0,0,0}, b1 = {0,0,0,0,0,0,0,0};
      if (keyr < N_){
        b0 = *(const bf16x8*)(kbb + (size_t)keyr*DH_ + kh*8);
        b1 = *(const bf16x8*)(kbb + (size_t)keyr*DH_ + 32 + kh*8);
      }
      f32x4 d = (f32x4){0.f,0.f,0.f,0.f};
      d = __builtin_amdgcn_mfma_f32_16x16x32_bf16(aq0, b0, d, 0,0,0);
      d = __builtin_amdgcn_mfma_f32_16x16x32_bf16(aq1, b1, d, 0,0,0);
      int col = tile*16 - keyoff + lr;
      #pragma unroll
      for (int rg=0; rg<4; ++rg)
        S[kh*4+rg][col] = d[rg];
    }
    __syncthreads();
    #pragma unroll
    for (int s=0; s<5; ++s){
      int sg = half*5 + s;
      int k = sg*64 + lane;
      if (k < N_){
        #pragma unroll
        for (int r=0;r<4;++r) acc[r][sg] = S[wave*4+r][k - keyoff];
      }
    }
    __syncthreads();
  }

  // ---- top-k (ballot radix) + masked softmax + P store ----
  #pragma unroll
  for (int r=0;r<4;++r){
    const int lrow = wave*4 + r;
    const int n = row0 + lrow;
    const bool rv = (n < N_);
    float sc[10]; unsigned u[10];
    #pragma unroll
    for (int s=0;s<10;++s) sc[s] = acc[r][s]*0.125f;
    #pragma unroll
    for (int s=0;s<10;++s){
      int k = s*64 + lane;
      bool vt = (k >= 1) && (k < N_);
      float uv = sc[s] + (k < N_ ? expl_s[k] : 0.f);
      u[s] = vt ? sortkey(uv) : 0u;
    }
    unsigned T = 0u;
    for (int bit=31; bit>=0; --bit){
      unsigned cand = T | (1u << bit);
      int c = 0;
      #pragma unroll
      for (int s=0;s<10;++s) c += (int)__popcll(__ballot(u[s] >= cand));
      if (c >= KKEEP) T = cand;
    }
    int cgt = 0;
    #pragma unroll
    for (int s=0;s<10;++s) cgt += (int)__popcll(__ballot(u[s] > T));
    const int rem = KKEEP - cgt;
    unsigned long long em[10];
    #pragma unroll
    for (int s=0;s<10;++s) em[s] = __ballot(u[s] == T);
    const unsigned long long below = lane ? (~0ull >> (64 - lane)) : 0ull;
    bool keep[10];
    int pref = 0;
    #pragma unroll
    for (int s=0;s<10;++s){
      int k = s*64 + lane;
      bool kp2 = false;
      if (k == 0) kp2 = true;
      else if (k < N_){
        if (u[s] > T) kp2 = true;
        else if (u[s] == T) kp2 = (pref + __popcll(em[s] & below)) < rem;
      }
      keep[s] = kp2;
      pref += __popcll(em[s]);
    }
    float mx = -3.4e38f;
    #pragma unroll
    for (int s=0;s<10;++s) if (keep[s]) mx = fmaxf(mx, sc[s]);
    mx = wredmaxf(mx);
    float p[10]; float den = 0.f;
    #pragma unroll
    for (int s=0;s<10;++s){ p[s] = keep[s] ? __expf(sc[s]-mx) : 0.f; den += p[s]; }
    den = wredsumf(den);
    const float inv = 1.0f/den;
    #pragma unroll
    for (int s=0;s<10;++s){
      int k = s*64 + lane;
      if (k < N_) pus[lrow][k] = f2bu(p[s]*inv);
      if (rv && keep[s]) atomicAdd(&cnt_s[k < N_ ? k : 0], 1);
    }
  }

  // ---- PV (unchanged): each wave its own 4 rows ----
  float o0=0.f,o1=0.f,o2=0.f,o3=0.f;
  const unsigned short* vbb = vw + (size_t)bh*N_*DH_;
  const int w4 = wave*4;
  #pragma unroll 2
  for (int kp=0; kp<288; ++kp){
    float v0 = b2f(vbb[(size_t)(2*kp)*DH_ + lane]);
    float v1 = b2f(vbb[(size_t)(2*kp+1)*DH_ + lane]);
    unsigned int p0 = *(const unsigned int*)&pus[w4+0][2*kp];
    unsigned int p1 = *(const unsigned int*)&pus[w4+1][2*kp];
    unsigned int p2 = *(const unsigned int*)&pus[w4+2][2*kp];
    unsigned int p3 = *(const unsigned int*)&pus[w4+3][2*kp];
    o0 = fmaf(lo16(p0), v0, fmaf(hi16(p0), v1, o0));
    o1 = fmaf(lo16(p1), v0, fmaf(hi16(p1), v1, o1));
    o2 = fmaf(lo16(p2), v0, fmaf(hi16(p2), v1, o2));
    o3 = fmaf(lo16(p3), v0, fmaf(hi16(p3), v1, o3));
  }
  {
    float v0 = b2f(vbb[(size_t)576*DH_ + lane]);
    o0 = fmaf(b2f(pus[w4+0][576]), v0, o0);
    o1 = fmaf(b2f(pus[w4+1][576]), v0, o1);
    o2 = fmaf(b2f(pus[w4+2][576]), v0, o2);
    o3 = fmaf(b2f(pus[w4+3][576]), v0, o3);
  }
  {
    int n0 = row0 + w4;
    if (n0+0 < N_) ctx[((size_t)bh*N_ + n0+0)*DH_ + lane] = f2bu(o0);
    if (n0+1 < N_) ctx[((size_t)bh*N_ + n0+1)*DH_ + lane] = f2bu(o1);
    if (n0+2 < N_) ctx[((size_t)bh*N_ + n0+2)*DH_ + lane] = f2bu(o2);
    if (n0+3 < N_) ctx[((size_t)bh*N_ + n0+3)*DH_ + lane] = f2bu(o3);
  }
  __syncthreads();
  for (int k2=tid; k2<N_; k2+=256){
    int c2 = cnt_s[k2];
    if (c2) atomicAdd(&delta[h*N_ + k2], c2);
  }
}

// ---------------- kernel 3: output projection via MFMA -> FP32 out (unchanged) ----------------
__global__ __launch_bounds__(256) void gemm_proj_mfma(
    const unsigned short* __restrict__ ctxp, const float* __restrict__ W,
    const float* __restrict__ bias, float* __restrict__ out)
{
  __shared__ unsigned short As[128][40];
  __shared__ unsigned short Bs[128][40];
  const int tid = threadIdx.x;
  const int lane = tid & 63, wave = tid >> 6;
  const int wm = wave >> 1, wn = wave & 1;
  const int lr = lane & 15, kh = lane >> 4;
  const int bm = blockIdx.x*128, bn = blockIdx.y*128;
  const int srow = tid >> 1, shalf = tid & 1;

  f32x4 acc[4][4];
  #pragma unroll
  for (int i=0;i<4;++i)
    #pragma unroll
    for (int j=0;j<4;++j) acc[i][j] = (f32x4){0.f,0.f,0.f,0.f};

  const int m_s = bm + srow;
  const int bb = m_s / N_, nn = m_s - bb*N_;

  for (int k0=0; k0<1024; k0+=32){
    __syncthreads();
    {
      uint4 a0 = {0,0,0,0}, a1 = {0,0,0,0};
      if (m_s < M_){
        int hh = k0 >> 6, dd = (k0 & 63) + shalf*16;
        const uint4* s = (const uint4*)(ctxp + ((size_t)(bb*H_ + hh)*N_ + nn)*DH_ + dd);
        a0 = s[0]; a1 = s[1];
      }
      *(uint4*)&As[srow][shalf*16]   = a0;
      *(uint4*)&As[srow][shalf*16+8] = a1;
      unsigned short t16[16];
      const float4* sw = (const float4*)(W + (size_t)(bn+srow)*1024 + k0 + shalf*16);
      #pragma unroll
      for (int g=0; g<4; ++g){
        float4 v = sw[g];
        t16[g*4+0]=f2bu(v.x); t16[g*4+1]=f2bu(v.y); t16[g*4+2]=f2bu(v.z); t16[g*4+3]=f2bu(v.w);
      }
      *(uint4*)&Bs[srow][shalf*16]   = *(uint4*)&t16[0];
      *(uint4*)&Bs[srow][shalf*16+8] = *(uint4*)&t16[8];
    }
    __syncthreads();
    bf16x8 af[4], bfr[4];
    #pragma unroll
    for (int f=0; f<4; ++f){
      af[f]  = *(const bf16x8*)&As[wm*64 + f*16 + lr][kh*8];
      bfr[f] = *(const bf16x8*)&Bs[wn*64 + f*16 + lr][kh*8];
    }
    #pragma unroll
    for (int fm=0; fm<4; ++fm)
      #pragma unroll
      for (int fn=0; fn<4; ++fn)
        acc[fm][fn] = __builtin_amdgcn_mfma_f32_16x16x32_bf16(af[fm], bfr[fn], acc[fm][fn], 0,0,0);
  }
  float bv[4];
  #pragma unroll
  for (int fn=0; fn<4; ++fn) bv[fn] = bias[bn + wn*64 + fn*16 + lr];
  #pragma unroll
  for (int fm=0; fm<4; ++fm){
    #pragma unroll
    for (int j=0; j<4; ++j){
      int m = bm + wm*64 + fm*16 + kh*4 + j;
      if (m >= M_) continue;
      #pragma unroll
      for (int fn=0; fn<4; ++fn){
        int c = bn + wn*64 + fn*16 + lr;
        out[(size_t)m*1024 + c] = acc[fm][fn][j] + bv[fn];
      }
    }
  }
}

// ---------------- kernel 4: score_delta int -> FP32 tail of d_out ----------------
__global__ void delta_to_f32(const int* __restrict__ delta, float* __restrict__ outd){
  int i = blockIdx.x*256 + threadIdx.x;
  if (i < H_*N_) outd[i] = (float)delta[i];
}

extern "C" void kernel_launch(void* const* d_in, const int* in_sizes, int n_in,
                              void* d_out, int out_size, void* d_ws, size_t ws_size,
                              hipStream_t stream) {
  const float* x      = (const float*)d_in[0];
  const float* qkv_w  = (const float*)d_in[1];
  const float* proj_w = (const float*)d_in[2];
  const float* proj_b = (const float*)d_in[3];
  const float* ucb    = (const float*)d_in[4];
  const int*   counter= (const int*)d_in[5];

  float* outO = (float*)d_out;
  float* outD = outO + ((size_t)out_size - (size_t)H_*N_);

  unsigned short* qb = (unsigned short*)d_ws;   // [bh][n][64]; doubles as ctx
  unsigned short* kb = qb + (size_t)M_*C_;
  unsigned short* vb = kb + (size_t)M_*C_;
  int*         delta = (int*)(vb + (size_t)M_*C_);

  hipMemsetAsync(delta, 0, (size_t)H_*N_*sizeof(int), stream);
  gemm_qkv_mfma<<<dim3(73,24), 256, 0, stream>>>(x, qkv_w, qb, kb, vb);
  attn_kernel<<<dim3(256*37), 256, 0, stream>>>(qb, kb, vb, ucb, counter, qb /*ctx alias*/, delta);
  gemm_proj_mfma<<<dim3(73,8), 256, 0, stream>>>(qb, proj_w, proj_b, outO);
  delta_to_f32<<<dim3(37), 256, 0, stream>>>(delta, outD);
}

// Round 9
// 532.800 us; speedup vs baseline: 6.6525x; 1.5007x over previous
//
#include <hip/hip_runtime.h>
#include <hip/hip_bf16.h>

#define B_ 16
#define N_ 577
#define C_ 1024
#define H_ 16
#define DH_ 64
#define M_ (B_*N_)          // 9232
#define KKEEP 144           // int(576 * 0.25)
#define VTP 584             // padded n-stride of transposed V (mult of 8, >=577)

typedef __attribute__((ext_vector_type(8))) short bf16x8;
typedef __attribute__((ext_vector_type(4))) float f32x4;

// ---------------- helpers ----------------
__device__ __forceinline__ float b2f(unsigned short u){ return __uint_as_float(((unsigned int)u) << 16); }
__device__ __forceinline__ float lo16(unsigned int u){ return __uint_as_float(u << 16); }
__device__ __forceinline__ float hi16(unsigned int u){ return __uint_as_float(u & 0xffff0000u); }
__device__ __forceinline__ unsigned short f2bu(float f){
  __hip_bfloat16 h = __float2bfloat16(f);
  return *(unsigned short*)&h;
}
__device__ __forceinline__ float wredmaxf(float v){
  #pragma unroll
  for (int m=1;m<64;m<<=1) v = fmaxf(v, __shfl_xor(v, m, 64));
  return v;
}
__device__ __forceinline__ float wredsumf(float v){
  #pragma unroll
  for (int m=1;m<64;m<<=1) v += __shfl_xor(v, m, 64);
  return v;
}
__device__ __forceinline__ unsigned sortkey(float f){
  unsigned i = __float_as_uint(f);
  return (i & 0x80000000u) ? ~i : (i | 0x80000000u);
}

// ---------------- kernel 1: QKV GEMM via MFMA; V scattered TRANSPOSED ----------------
__global__ __launch_bounds__(256) void gemm_qkv_mfma(
    const float* __restrict__ X, const float* __restrict__ W,
    unsigned short* __restrict__ qb, unsigned short* __restrict__ kb,
    unsigned short* __restrict__ vt)
{
  __shared__ unsigned short As[128][40];
  __shared__ unsigned short Bs[128][40];
  const int tid = threadIdx.x;
  const int lane = tid & 63, wave = tid >> 6;
  const int wm = wave >> 1, wn = wave & 1;
  const int lr = lane & 15, kh = lane >> 4;
  const int bm = blockIdx.x*128, bn = blockIdx.y*128;
  const int srow = tid >> 1, shalf = tid & 1;

  f32x4 acc[4][4];
  #pragma unroll
  for (int i=0;i<4;++i)
    #pragma unroll
    for (int j=0;j<4;++j) acc[i][j] = (f32x4){0.f,0.f,0.f,0.f};

  for (int k0=0; k0<1024; k0+=32){
    __syncthreads();
    {
      unsigned short t16[16];
      int m = bm + srow;
      if (m < M_){
        const float4* s = (const float4*)(X + (size_t)m*1024 + k0 + shalf*16);
        #pragma unroll
        for (int g=0; g<4; ++g){
          float4 v = s[g];
          t16[g*4+0]=f2bu(v.x); t16[g*4+1]=f2bu(v.y); t16[g*4+2]=f2bu(v.z); t16[g*4+3]=f2bu(v.w);
        }
      } else {
        #pragma unroll
        for (int g=0; g<16; ++g) t16[g]=0;
      }
      *(uint4*)&As[srow][shalf*16]   = *(uint4*)&t16[0];
      *(uint4*)&As[srow][shalf*16+8] = *(uint4*)&t16[8];

      const float4* sw = (const float4*)(W + (size_t)(bn+srow)*1024 + k0 + shalf*16);
      #pragma unroll
      for (int g=0; g<4; ++g){
        float4 v = sw[g];
        t16[g*4+0]=f2bu(v.x); t16[g*4+1]=f2bu(v.y); t16[g*4+2]=f2bu(v.z); t16[g*4+3]=f2bu(v.w);
      }
      *(uint4*)&Bs[srow][shalf*16]   = *(uint4*)&t16[0];
      *(uint4*)&Bs[srow][shalf*16+8] = *(uint4*)&t16[8];
    }
    __syncthreads();
    bf16x8 af[4], bfr[4];
    #pragma unroll
    for (int f=0; f<4; ++f){
      af[f]  = *(const bf16x8*)&As[wm*64 + f*16 + lr][kh*8];
      bfr[f] = *(const bf16x8*)&Bs[wn*64 + f*16 + lr][kh*8];
    }
    #pragma unroll
    for (int fm=0; fm<4; ++fm)
      #pragma unroll
      for (int fn=0; fn<4; ++fn)
        acc[fm][fn] = __builtin_amdgcn_mfma_f32_16x16x32_bf16(af[fm], bfr[fn], acc[fm][fn], 0,0,0);
  }
  #pragma unroll
  for (int fm=0; fm<4; ++fm){
    #pragma unroll
    for (int j=0; j<4; ++j){
      int m = bm + wm*64 + fm*16 + kh*4 + j;
      if (m >= M_) continue;
      int b = m / N_, n = m - b*N_;
      #pragma unroll
      for (int fn=0; fn<4; ++fn){
        int c = bn + wn*64 + fn*16 + lr;
        int three = c >> 10, hh = (c >> 6) & 15, dd = c & 63;
        unsigned short val = f2bu(acc[fm][fn][j]);
        if (three == 0)      qb[((size_t)(b*H_ + hh)*N_ + n)*DH_ + dd] = val;
        else if (three == 1) kb[((size_t)(b*H_ + hh)*N_ + n)*DH_ + dd] = val;
        else                 vt[((size_t)(b*H_ + hh)*DH_ + dd)*VTP + n] = val;  // transposed
      }
    }
  }
}

// ---------------- kernel 2: fused attention (QK + PV via MFMA, ballot radix) ----------------
__global__ __launch_bounds__(256,5) void attn_kernel(
    const unsigned short* __restrict__ qw, const unsigned short* __restrict__ kw,
    const unsigned short* __restrict__ vt,
    const float* __restrict__ ucb, const int* __restrict__ counter_p,
    unsigned short* __restrict__ ctx, int* __restrict__ delta)
{
  __shared__ __align__(16) float S[16][320];       // 20480B; P (bf16) aliases after QK
  __shared__ float expl_s[584];
  __shared__ int   cnt_s[584];
  unsigned short (*pus)[584] = (unsigned short (*)[584])&S[0][0];   // 18688B <= 20480B

  const int tid = threadIdx.x;
  const int lane = tid & 63, wave = tid >> 6;
  const int lr = lane & 15, kh = lane >> 4;
  const int blk = blockIdx.x;
  const int bh = blk / 37, tileq = blk % 37;
  const int h = bh & 15;
  const int row0 = tileq * 16;

  const float logc = logf((float)(*counter_p) + 1.0f);
  for (int k2=tid; k2<N_; k2+=256){
    cnt_s[k2] = 0;
    expl_s[k2] = (k2==0) ? 0.f : sqrtf(logc / (ucb[h*N_ + k2] + 1e-6f));
  }

  // ---- QK^T via MFMA ----
  const unsigned short* qbb = qw + (size_t)bh*N_*DH_;
  const unsigned short* kbb = kw + (size_t)bh*N_*DH_;
  bf16x8 aq0 = {0,0,0,0,0,0,0,0}, aq1 = {0,0,0,0,0,0,0,0};
  {
    int qr = row0 + lr;
    if (qr < N_){
      aq0 = *(const bf16x8*)(qbb + (size_t)qr*DH_ + kh*8);
      aq1 = *(const bf16x8*)(qbb + (size_t)qr*DH_ + 32 + kh*8);
    }
  }

  float acc[4][10];
  #pragma unroll
  for (int r=0;r<4;++r)
    #pragma unroll
    for (int s=0;s<10;++s) acc[r][s]=0.f;

  #pragma unroll
  for (int half=0; half<2; ++half){
    const int t0 = half ? 20 : 0, t1 = half ? 37 : 20, keyoff = half*320;
    for (int tile = t0 + wave; tile < t1; tile += 4){
      int keyr = tile*16 + lr;
      bf16x8 b0 = {0,0,0,0,0,0,0,0}, b1 = {0,0,0,0,0,0,0,0};
      if (keyr < N_){
        b0 = *(const bf16x8*)(kbb + (size_t)keyr*DH_ + kh*8);
        b1 = *(const bf16x8*)(kbb + (size_t)keyr*DH_ + 32 + kh*8);
      }
      f32x4 d = (f32x4){0.f,0.f,0.f,0.f};
      d = __builtin_amdgcn_mfma_f32_16x16x32_bf16(aq0, b0, d, 0,0,0);
      d = __builtin_amdgcn_mfma_f32_16x16x32_bf16(aq1, b1, d, 0,0,0);
      int col = tile*16 - keyoff + lr;
      #pragma unroll
      for (int rg=0; rg<4; ++rg)
        S[kh*4+rg][col] = d[rg];
    }
    __syncthreads();
    #pragma unroll
    for (int s=0; s<5; ++s){
      int sg = half*5 + s;
      int k = sg*64 + lane;
      if (k < N_){
        #pragma unroll
        for (int r=0;r<4;++r) acc[r][sg] = S[wave*4+r][k - keyoff];
      }
    }
    __syncthreads();
  }

  // ---- top-k (ballot radix) + masked softmax + P store ----
  #pragma unroll
  for (int r=0;r<4;++r){
    const int lrow = wave*4 + r;
    const int n = row0 + lrow;
    const bool rv = (n < N_);
    float sc[10]; unsigned u[10];
    #pragma unroll
    for (int s=0;s<10;++s) sc[s] = acc[r][s]*0.125f;
    #pragma unroll
    for (int s=0;s<10;++s){
      int k = s*64 + lane;
      bool vt2 = (k >= 1) && (k < N_);
      float uv = sc[s] + (k < N_ ? expl_s[k] : 0.f);
      u[s] = vt2 ? sortkey(uv) : 0u;
    }
    unsigned T = 0u;
    for (int bit=31; bit>=0; --bit){
      unsigned cand = T | (1u << bit);
      int c = 0;
      #pragma unroll
      for (int s=0;s<10;++s) c += (int)__popcll(__ballot(u[s] >= cand));
      if (c >= KKEEP) T = cand;
    }
    int cgt = 0;
    #pragma unroll
    for (int s=0;s<10;++s) cgt += (int)__popcll(__ballot(u[s] > T));
    const int rem = KKEEP - cgt;
    unsigned long long em[10];
    #pragma unroll
    for (int s=0;s<10;++s) em[s] = __ballot(u[s] == T);
    const unsigned long long below = lane ? (~0ull >> (64 - lane)) : 0ull;
    bool keep[10];
    int pref = 0;
    #pragma unroll
    for (int s=0;s<10;++s){
      int k = s*64 + lane;
      bool kp2 = false;
      if (k == 0) kp2 = true;
      else if (k < N_){
        if (u[s] > T) kp2 = true;
        else if (u[s] == T) kp2 = (pref + __popcll(em[s] & below)) < rem;
      }
      keep[s] = kp2;
      pref += __popcll(em[s]);
    }
    float mx = -3.4e38f;
    #pragma unroll
    for (int s=0;s<10;++s) if (keep[s]) mx = fmaxf(mx, sc[s]);
    mx = wredmaxf(mx);
    float p[10]; float den = 0.f;
    #pragma unroll
    for (int s=0;s<10;++s){ p[s] = keep[s] ? __expf(sc[s]-mx) : 0.f; den += p[s]; }
    den = wredsumf(den);
    const float inv = 1.0f/den;
    #pragma unroll
    for (int s=0;s<10;++s){
      int k = s*64 + lane;
      if (k < N_) pus[lrow][k] = f2bu(p[s]*inv);
      if (rv && keep[s]) atomicAdd(&cnt_s[k < N_ ? k : 0], 1);
    }
  }
  __syncthreads();   // PV reads all 16 P rows

  // ---- PV via MFMA: O[16q][64d]; wave handles d-block wave*16 ----
  {
    const int d0 = wave*16;
    const unsigned short* vtb = vt + ((size_t)bh*DH_ + d0 + lr)*VTP;
    f32x4 od = (f32x4){0.f,0.f,0.f,0.f};
    #pragma unroll 3
    for (int kb2=0; kb2<18; ++kb2){
      bf16x8 pa  = *(const bf16x8*)&pus[lr][kb2*32 + kh*8];
      bf16x8 vb8 = *(const bf16x8*)(vtb + kb2*32 + kh*8);
      od = __builtin_amdgcn_mfma_f32_16x16x32_bf16(pa, vb8, od, 0,0,0);
    }
    const float v576 = b2f(vtb[576]);
    #pragma unroll
    for (int rg=0; rg<4; ++rg){
      int q = kh*4 + rg;
      float o = fmaf(b2f(pus[q][576]), v576, od[rg]);
      int n0 = row0 + q;
      if (n0 < N_) ctx[((size_t)bh*N_ + n0)*DH_ + d0 + lr] = f2bu(o);
    }
  }
  __syncthreads();
  for (int k2=tid; k2<N_; k2+=256){
    int c2 = cnt_s[k2];
    if (c2) atomicAdd(&delta[h*N_ + k2], c2);
  }
}

// ---------------- kernel 3: output projection via MFMA -> FP32 out (unchanged) ----------------
__global__ __launch_bounds__(256) void gemm_proj_mfma(
    const unsigned short* __restrict__ ctxp, const float* __restrict__ W,
    const float* __restrict__ bias, float* __restrict__ out)
{
  __shared__ unsigned short As[128][40];
  __shared__ unsigned short Bs[128][40];
  const int tid = threadIdx.x;
  const int lane = tid & 63, wave = tid >> 6;
  const int wm = wave >> 1, wn = wave & 1;
  const int lr = lane & 15, kh = lane >> 4;
  const int bm = blockIdx.x*128, bn = blockIdx.y*128;
  const int srow = tid >> 1, shalf = tid & 1;

  f32x4 acc[4][4];
  #pragma unroll
  for (int i=0;i<4;++i)
    #pragma unroll
    for (int j=0;j<4;++j) acc[i][j] = (f32x4){0.f,0.f,0.f,0.f};

  const int m_s = bm + srow;
  const int bb = m_s / N_, nn = m_s - bb*N_;

  for (int k0=0; k0<1024; k0+=32){
    __syncthreads();
    {
      uint4 a0 = {0,0,0,0}, a1 = {0,0,0,0};
      if (m_s < M_){
        int hh = k0 >> 6, dd = (k0 & 63) + shalf*16;
        const uint4* s = (const uint4*)(ctxp + ((size_t)(bb*H_ + hh)*N_ + nn)*DH_ + dd);
        a0 = s[0]; a1 = s[1];
      }
      *(uint4*)&As[srow][shalf*16]   = a0;
      *(uint4*)&As[srow][shalf*16+8] = a1;
      unsigned short t16[16];
      const float4* sw = (const float4*)(W + (size_t)(bn+srow)*1024 + k0 + shalf*16);
      #pragma unroll
      for (int g=0; g<4; ++g){
        float4 v = sw[g];
        t16[g*4+0]=f2bu(v.x); t16[g*4+1]=f2bu(v.y); t16[g*4+2]=f2bu(v.z); t16[g*4+3]=f2bu(v.w);
      }
      *(uint4*)&Bs[srow][shalf*16]   = *(uint4*)&t16[0];
      *(uint4*)&Bs[srow][shalf*16+8] = *(uint4*)&t16[8];
    }
    __syncthreads();
    bf16x8 af[4], bfr[4];
    #pragma unroll
    for (int f=0; f<4; ++f){
      af[f]  = *(const bf16x8*)&As[wm*64 + f*16 + lr][kh*8];
      bfr[f] = *(const bf16x8*)&Bs[wn*64 + f*16 + lr][kh*8];
    }
    #pragma unroll
    for (int fm=0; fm<4; ++fm)
      #pragma unroll
      for (int fn=0; fn<4; ++fn)
        acc[fm][fn] = __builtin_amdgcn_mfma_f32_16x16x32_bf16(af[fm], bfr[fn], acc[fm][fn], 0,0,0);
  }
  float bv[4];
  #pragma unroll
  for (int fn=0; fn<4; ++fn) bv[fn] = bias[bn + wn*64 + fn*16 + lr];
  #pragma unroll
  for (int fm=0; fm<4; ++fm){
    #pragma unroll
    for (int j=0; j<4; ++j){
      int m = bm + wm*64 + fm*16 + kh*4 + j;
      if (m >= M_) continue;
      #pragma unroll
      for (int fn=0; fn<4; ++fn){
        int c = bn + wn*64 + fn*16 + lr;
        out[(size_t)m*1024 + c] = acc[fm][fn][j] + bv[fn];
      }
    }
  }
}

// ---------------- kernel 4: score_delta int -> FP32 tail of d_out ----------------
__global__ void delta_to_f32(const int* __restrict__ delta, float* __restrict__ outd){
  int i = blockIdx.x*256 + threadIdx.x;
  if (i < H_*N_) outd[i] = (float)delta[i];
}

extern "C" void kernel_launch(void* const* d_in, const int* in_sizes, int n_in,
                              void* d_out, int out_size, void* d_ws, size_t ws_size,
                              hipStream_t stream) {
  const float* x      = (const float*)d_in[0];
  const float* qkv_w  = (const float*)d_in[1];
  const float* proj_w = (const float*)d_in[2];
  const float* proj_b = (const float*)d_in[3];
  const float* ucb    = (const float*)d_in[4];
  const int*   counter= (const int*)d_in[5];

  float* outO = (float*)d_out;
  float* outD = outO + ((size_t)out_size - (size_t)H_*N_);

  unsigned short* qb = (unsigned short*)d_ws;   // [bh][n][64]; doubles as ctx
  unsigned short* kb = qb + (size_t)M_*C_;
  unsigned short* vt = kb + (size_t)M_*C_;      // [bh][d][VTP] transposed V
  int*         delta = (int*)(vt + (size_t)B_*H_*DH_*VTP);

  hipMemsetAsync(delta, 0, (size_t)H_*N_*sizeof(int), stream);
  gemm_qkv_mfma<<<dim3(73,24), 256, 0, stream>>>(x, qkv_w, qb, kb, vt);
  attn_kernel<<<dim3(256*37), 256, 0, stream>>>(qb, kb, vt, ucb, counter, qb /*ctx alias*/, delta);
  gemm_proj_mfma<<<dim3(73,8), 256, 0, stream>>>(qb, proj_w, proj_b, outO);
  delta_to_f32<<<dim3(37), 256, 0, stream>>>(delta, outD);
}

// Round 10
// 453.818 us; speedup vs baseline: 7.8102x; 1.1740x over previous
//
#include <hip/hip_runtime.h>
#include <hip/hip_bf16.h>

#define B_ 16
#define N_ 577
#define C_ 1024
#define H_ 16
#define DH_ 64
#define M_ (B_*N_)          // 9232
#define KKEEP 144           // int(576 * 0.25)
#define VTP 584             // padded n-stride of transposed V (mult of 8, >=577)
#define SST 325             // S row stride (dwords), mod 32 = 5 -> <=2-way store conflicts

typedef __attribute__((ext_vector_type(8))) short bf16x8;
typedef __attribute__((ext_vector_type(4))) float f32x4;

// ---------------- helpers ----------------
__device__ __forceinline__ float b2f(unsigned short u){ return __uint_as_float(((unsigned int)u) << 16); }
__device__ __forceinline__ unsigned short f2bu(float f){
  __hip_bfloat16 h = __float2bfloat16(f);
  return *(unsigned short*)&h;
}
__device__ __forceinline__ float wredmaxf(float v){
  #pragma unroll
  for (int m=1;m<64;m<<=1) v = fmaxf(v, __shfl_xor(v, m, 64));
  return v;
}
__device__ __forceinline__ float wredsumf(float v){
  #pragma unroll
  for (int m=1;m<64;m<<=1) v += __shfl_xor(v, m, 64);
  return v;
}

// ---------------- kernel 1: QKV GEMM via MFMA; V scattered TRANSPOSED ----------------
__global__ __launch_bounds__(256) void gemm_qkv_mfma(
    const float* __restrict__ X, const float* __restrict__ W,
    unsigned short* __restrict__ qb, unsigned short* __restrict__ kb,
    unsigned short* __restrict__ vt)
{
  __shared__ unsigned short As[128][40];
  __shared__ unsigned short Bs[128][40];
  const int tid = threadIdx.x;
  const int lane = tid & 63, wave = tid >> 6;
  const int wm = wave >> 1, wn = wave & 1;
  const int lr = lane & 15, kh = lane >> 4;
  const int bm = blockIdx.x*128, bn = blockIdx.y*128;
  const int srow = tid >> 1, shalf = tid & 1;

  f32x4 acc[4][4];
  #pragma unroll
  for (int i=0;i<4;++i)
    #pragma unroll
    for (int j=0;j<4;++j) acc[i][j] = (f32x4){0.f,0.f,0.f,0.f};

  for (int k0=0; k0<1024; k0+=32){
    __syncthreads();
    {
      unsigned short t16[16];
      int m = bm + srow;
      if (m < M_){
        const float4* s = (const float4*)(X + (size_t)m*1024 + k0 + shalf*16);
        #pragma unroll
        for (int g=0; g<4; ++g){
          float4 v = s[g];
          t16[g*4+0]=f2bu(v.x); t16[g*4+1]=f2bu(v.y); t16[g*4+2]=f2bu(v.z); t16[g*4+3]=f2bu(v.w);
        }
      } else {
        #pragma unroll
        for (int g=0; g<16; ++g) t16[g]=0;
      }
      *(uint4*)&As[srow][shalf*16]   = *(uint4*)&t16[0];
      *(uint4*)&As[srow][shalf*16+8] = *(uint4*)&t16[8];

      const float4* sw = (const float4*)(W + (size_t)(bn+srow)*1024 + k0 + shalf*16);
      #pragma unroll
      for (int g=0; g<4; ++g){
        float4 v = sw[g];
        t16[g*4+0]=f2bu(v.x); t16[g*4+1]=f2bu(v.y); t16[g*4+2]=f2bu(v.z); t16[g*4+3]=f2bu(v.w);
      }
      *(uint4*)&Bs[srow][shalf*16]   = *(uint4*)&t16[0];
      *(uint4*)&Bs[srow][shalf*16+8] = *(uint4*)&t16[8];
    }
    __syncthreads();
    bf16x8 af[4], bfr[4];
    #pragma unroll
    for (int f=0; f<4; ++f){
      af[f]  = *(const bf16x8*)&As[wm*64 + f*16 + lr][kh*8];
      bfr[f] = *(const bf16x8*)&Bs[wn*64 + f*16 + lr][kh*8];
    }
    #pragma unroll
    for (int fm=0; fm<4; ++fm)
      #pragma unroll
      for (int fn=0; fn<4; ++fn)
        acc[fm][fn] = __builtin_amdgcn_mfma_f32_16x16x32_bf16(af[fm], bfr[fn], acc[fm][fn], 0,0,0);
  }
  #pragma unroll
  for (int fm=0; fm<4; ++fm){
    #pragma unroll
    for (int j=0; j<4; ++j){
      int m = bm + wm*64 + fm*16 + kh*4 + j;
      if (m >= M_) continue;
      int b = m / N_, n = m - b*N_;
      #pragma unroll
      for (int fn=0; fn<4; ++fn){
        int c = bn + wn*64 + fn*16 + lr;
        int three = c >> 10, hh = (c >> 6) & 15, dd = c & 63;
        unsigned short val = f2bu(acc[fm][fn][j]);
        if (three == 0)      qb[((size_t)(b*H_ + hh)*N_ + n)*DH_ + dd] = val;
        else if (three == 1) kb[((size_t)(b*H_ + hh)*N_ + n)*DH_ + dd] = val;
        else                 vt[((size_t)(b*H_ + hh)*DH_ + dd)*VTP + n] = val;  // transposed
      }
    }
  }
}

// ---------------- kernel 2: fused attention (QK + PV via MFMA, 16-bit quantized radix) ----------------
__global__ __launch_bounds__(256,6) void attn_kernel(
    const unsigned short* __restrict__ qw, const unsigned short* __restrict__ kw,
    const unsigned short* __restrict__ vt,
    const float* __restrict__ ucb, const int* __restrict__ counter_p,
    unsigned short* __restrict__ ctx, int* __restrict__ delta)
{
  __shared__ __align__(16) float S[16][SST];       // 20800B; P (bf16, stride 584) aliases after QK
  __shared__ float expl_s[584];
  __shared__ int   cnt_s[584];
  unsigned short (*pus)[584] = (unsigned short (*)[584])&S[0][0];   // 18688B <= 20800B

  const int tid = threadIdx.x;
  const int lane = tid & 63, wave = tid >> 6;
  const int lr = lane & 15, kh = lane >> 4;
  const int blk = blockIdx.x;
  const int bh = blk / 37, tileq = blk % 37;
  const int h = bh & 15;
  const int row0 = tileq * 16;

  const float logc = logf((float)(*counter_p) + 1.0f);
  for (int k2=tid; k2<N_; k2+=256){
    cnt_s[k2] = 0;
    expl_s[k2] = (k2==0) ? 0.f : sqrtf(logc / (ucb[h*N_ + k2] + 1e-6f));
  }

  // ---- QK^T via MFMA ----
  const unsigned short* qbb = qw + (size_t)bh*N_*DH_;
  const unsigned short* kbb = kw + (size_t)bh*N_*DH_;
  bf16x8 aq0 = {0,0,0,0,0,0,0,0}, aq1 = {0,0,0,0,0,0,0,0};
  {
    int qr = row0 + lr;
    if (qr < N_){
      aq0 = *(const bf16x8*)(qbb + (size_t)qr*DH_ + kh*8);
      aq1 = *(const bf16x8*)(qbb + (size_t)qr*DH_ + 32 + kh*8);
    }
  }

  float acc[4][10];
  #pragma unroll
  for (int r=0;r<4;++r)
    #pragma unroll
    for (int s=0;s<10;++s) acc[r][s]=0.f;

  #pragma unroll
  for (int half=0; half<2; ++half){
    const int t0 = half ? 20 : 0, t1 = half ? 37 : 20, keyoff = half*320;
    for (int tile = t0 + wave; tile < t1; tile += 4){
      int keyr = tile*16 + lr;
      bf16x8 b0 = {0,0,0,0,0,0,0,0}, b1 = {0,0,0,0,0,0,0,0};
      if (keyr < N_){
        b0 = *(const bf16x8*)(kbb + (size_t)keyr*DH_ + kh*8);
        b1 = *(const bf16x8*)(kbb + (size_t)keyr*DH_ + 32 + kh*8);
      }
      f32x4 d = (f32x4){0.f,0.f,0.f,0.f};
      d = __builtin_amdgcn_mfma_f32_16x16x32_bf16(aq0, b0, d, 0,0,0);
      d = __builtin_amdgcn_mfma_f32_16x16x32_bf16(aq1, b1, d, 0,0,0);
      int col = tile*16 - keyoff + lr;
      #pragma unroll
      for (int rg=0; rg<4; ++rg)
        S[kh*4+rg][col] = d[rg];
    }
    __syncthreads();
    #pragma unroll
    for (int s=0; s<5; ++s){
      int sg = half*5 + s;
      int k = sg*64 + lane;
      if (k < N_){
        #pragma unroll
        for (int r=0;r<4;++r) acc[r][sg] = S[wave*4+r][k - keyoff];
      }
    }
    __syncthreads();
  }

  // ---- top-k (16-bit quantized ballot radix) + masked softmax + P store ----
  #pragma unroll
  for (int r=0;r<4;++r){
    const int lrow = wave*4 + r;
    const int n = row0 + lrow;
    const bool rv = (n < N_);
    float sc[10], uv[10]; bool vd[10];
    #pragma unroll
    for (int s=0;s<10;++s) sc[s] = acc[r][s]*0.125f;
    float mx0 = -3.4e38f, mn0 = 3.4e38f;
    #pragma unroll
    for (int s=0;s<10;++s){
      int k = s*64 + lane;
      vd[s] = (k >= 1) && (k < N_);
      uv[s] = sc[s] + (k < N_ ? expl_s[k] : 0.f);
      if (vd[s]){ mx0 = fmaxf(mx0, uv[s]); mn0 = fminf(mn0, uv[s]); }
    }
    const float mx1 = wredmaxf(mx0);
    const float mn1 = -wredmaxf(-mn0);
    const float scale = 65534.f / fmaxf(mx1 - mn1, 1e-30f);
    unsigned uq[10];
    #pragma unroll
    for (int s=0;s<10;++s)
      uq[s] = vd[s] ? (1u + (unsigned)((uv[s]-mn1)*scale)) : 0u;

    unsigned T = 0u;
    for (int bit=15; bit>=0; --bit){
      unsigned cand = T | (1u << bit);
      int c = 0;
      #pragma unroll
      for (int s=0;s<10;++s) c += (int)__popcll(__ballot(uq[s] >= cand));
      if (c >= KKEEP) T = cand;
    }
    int cgt = 0;
    #pragma unroll
    for (int s=0;s<10;++s) cgt += (int)__popcll(__ballot(uq[s] > T));
    const int rem = KKEEP - cgt;
    unsigned long long em[10];
    #pragma unroll
    for (int s=0;s<10;++s) em[s] = __ballot(uq[s] == T);
    const unsigned long long below = lane ? (~0ull >> (64 - lane)) : 0ull;
    bool keep[10];
    int pref = 0;
    #pragma unroll
    for (int s=0;s<10;++s){
      int k = s*64 + lane;
      bool kp2 = false;
      if (k == 0) kp2 = true;
      else if (k < N_){
        if (uq[s] > T) kp2 = true;
        else if (uq[s] == T) kp2 = (pref + __popcll(em[s] & below)) < rem;
      }
      keep[s] = kp2;
      pref += __popcll(em[s]);
    }
    float mxs = -3.4e38f;
    #pragma unroll
    for (int s=0;s<10;++s) if (keep[s]) mxs = fmaxf(mxs, sc[s]);
    mxs = wredmaxf(mxs);
    float p[10]; float den = 0.f;
    #pragma unroll
    for (int s=0;s<10;++s){ p[s] = keep[s] ? __expf(sc[s]-mxs) : 0.f; den += p[s]; }
    den = wredsumf(den);
    const float inv = 1.0f/den;
    #pragma unroll
    for (int s=0;s<10;++s){
      int k = s*64 + lane;
      if (k < N_) pus[lrow][k] = f2bu(p[s]*inv);
      if (rv && keep[s]) atomicAdd(&cnt_s[k < N_ ? k : 0], 1);
    }
  }
  __syncthreads();   // PV reads all 16 P rows

  // ---- PV via MFMA: O[16q][64d]; wave handles d-block wave*16 ----
  {
    const int d0 = wave*16;
    const unsigned short* vtb = vt + ((size_t)bh*DH_ + d0 + lr)*VTP;
    f32x4 od = (f32x4){0.f,0.f,0.f,0.f};
    #pragma unroll 3
    for (int kb2=0; kb2<18; ++kb2){
      bf16x8 pa  = *(const bf16x8*)&pus[lr][kb2*32 + kh*8];
      bf16x8 vb8 = *(const bf16x8*)(vtb + kb2*32 + kh*8);
      od = __builtin_amdgcn_mfma_f32_16x16x32_bf16(pa, vb8, od, 0,0,0);
    }
    const float v576 = b2f(vtb[576]);
    #pragma unroll
    for (int rg=0; rg<4; ++rg){
      int q = kh*4 + rg;
      float o = fmaf(b2f(pus[q][576]), v576, od[rg]);
      int n0 = row0 + q;
      if (n0 < N_) ctx[((size_t)bh*N_ + n0)*DH_ + d0 + lr] = f2bu(o);
    }
  }
  __syncthreads();
  for (int k2=tid; k2<N_; k2+=256){
    int c2 = cnt_s[k2];
    if (c2) atomicAdd(&delta[h*N_ + k2], c2);
  }
}

// ---------------- kernel 3: output projection via MFMA -> FP32 out ----------------
__global__ __launch_bounds__(256) void gemm_proj_mfma(
    const unsigned short* __restrict__ ctxp, const float* __restrict__ W,
    const float* __restrict__ bias, float* __restrict__ out)
{
  __shared__ unsigned short As[128][40];
  __shared__ unsigned short Bs[128][40];
  const int tid = threadIdx.x;
  const int lane = tid & 63, wave = tid >> 6;
  const int wm = wave >> 1, wn = wave & 1;
  const int lr = lane & 15, kh = lane >> 4;
  const int bm = blockIdx.x*128, bn = blockIdx.y*128;
  const int srow = tid >> 1, shalf = tid & 1;

  f32x4 acc[4][4];
  #pragma unroll
  for (int i=0;i<4;++i)
    #pragma unroll
    for (int j=0;j<4;++j) acc[i][j] = (f32x4){0.f,0.f,0.f,0.f};

  const int m_s = bm + srow;
  const int bb = m_s / N_, nn = m_s - bb*N_;

  for (int k0=0; k0<1024; k0+=32){
    __syncthreads();
    {
      uint4 a0 = {0,0,0,0}, a1 = {0,0,0,0};
      if (m_s < M_){
        int hh = k0 >> 6, dd = (k0 & 63) + shalf*16;
        const uint4* s = (const uint4*)(ctxp + ((size_t)(bb*H_ + hh)*N_ + nn)*DH_ + dd);
        a0 = s[0]; a1 = s[1];
      }
      *(uint4*)&As[srow][shalf*16]   = a0;
      *(uint4*)&As[srow][shalf*16+8] = a1;
      unsigned short t16[16];
      const float4* sw = (const float4*)(W + (size_t)(bn+srow)*1024 + k0 + shalf*16);
      #pragma unroll
      for (int g=0; g<4; ++g){
        float4 v = sw[g];
        t16[g*4+0]=f2bu(v.x); t16[g*4+1]=f2bu(v.y); t16[g*4+2]=f2bu(v.z); t16[g*4+3]=f2bu(v.w);
      }
      *(uint4*)&Bs[srow][shalf*16]   = *(uint4*)&t16[0];
      *(uint4*)&Bs[srow][shalf*16+8] = *(uint4*)&t16[8];
    }
    __syncthreads();
    bf16x8 af[4], bfr[4];
    #pragma unroll
    for (int f=0; f<4; ++f){
      af[f]  = *(const bf16x8*)&As[wm*64 + f*16 + lr][kh*8];
      bfr[f] = *(const bf16x8*)&Bs[wn*64 + f*16 + lr][kh*8];
    }
    #pragma unroll
    for (int fm=0; fm<4; ++fm)
      #pragma unroll
      for (int fn=0; fn<4; ++fn)
        acc[fm][fn] = __builtin_amdgcn_mfma_f32_16x16x32_bf16(af[fm], bfr[fn], acc[fm][fn], 0,0,0);
  }
  float bv[4];
  #pragma unroll
  for (int fn=0; fn<4; ++fn) bv[fn] = bias[bn + wn*64 + fn*16 + lr];
  #pragma unroll
  for (int fm=0; fm<4; ++fm){
    #pragma unroll
    for (int j=0; j<4; ++j){
      int m = bm + wm*64 + fm*16 + kh*4 + j;
      if (m >= M_) continue;
      #pragma unroll
      for (int fn=0; fn<4; ++fn){
        int c = bn + wn*64 + fn*16 + lr;
        out[(size_t)m*1024 + c] = acc[fm][fn][j] + bv[fn];
      }
    }
  }
}

// ---------------- kernel 4: score_delta int -> FP32 tail of d_out ----------------
__global__ void delta_to_f32(const int* __restrict__ delta, float* __restrict__ outd){
  int i = blockIdx.x*256 + threadIdx.x;
  if (i < H_*N_) outd[i] = (float)delta[i];
}

extern "C" void kernel_launch(void* const* d_in, const int* in_sizes, int n_in,
                              void* d_out, int out_size, void* d_ws, size_t ws_size,
                              hipStream_t stream) {
  const float* x      = (const float*)d_in[0];
  const float* qkv_w  = (const float*)d_in[1];
  const float* proj_w = (const float*)d_in[2];
  const float* proj_b = (const float*)d_in[3];
  const float* ucb    = (const float*)d_in[4];
  const int*   counter= (const int*)d_in[5];

  float* outO = (float*)d_out;
  float* outD = outO + ((size_t)out_size - (size_t)H_*N_);

  unsigned short* qb = (unsigned short*)d_ws;   // [bh][n][64]; doubles as ctx
  unsigned short* kb = qb + (size_t)M_*C_;
  unsigned short* vt = kb + (size_t)M_*C_;      // [bh][d][VTP] transposed V
  int*         delta = (int*)(vt + (size_t)B_*H_*DH_*VTP);

  hipMemsetAsync(delta, 0, (size_t)H_*N_*sizeof(int), stream);
  gemm_qkv_mfma<<<dim3(73,24), 256, 0, stream>>>(x, qkv_w, qb, kb, vt);
  attn_kernel<<<dim3(256*37), 256, 0, stream>>>(qb, kb, vt, ucb, counter, qb /*ctx alias*/, delta);
  gemm_proj_mfma<<<dim3(73,8), 256, 0, stream>>>(qb, proj_w, proj_b, outO);
  delta_to_f32<<<dim3(37), 256, 0, stream>>>(delta, outD);
}

// Round 11
// 378.059 us; speedup vs baseline: 9.3753x; 1.2004x over previous
//
#include <hip/hip_runtime.h>
#include <hip/hip_bf16.h>

#define B_ 16
#define N_ 577
#define C_ 1024
#define H_ 16
#define DH_ 64
#define M_ (B_*N_)          // 9232
#define KKEEP 144           // int(576 * 0.25)
#define VTP 584             // padded n-stride of transposed V (mult of 8, >=584 covers 577..583 pad)
#define SST 325             // S row stride (dwords)

typedef __attribute__((ext_vector_type(8))) short bf16x8;
typedef __attribute__((ext_vector_type(4))) float f32x4;

// ---------------- helpers ----------------
__device__ __forceinline__ float b2f(unsigned short u){ return __uint_as_float(((unsigned int)u) << 16); }
__device__ __forceinline__ unsigned short f2bu(float f){
  __hip_bfloat16 h = __float2bfloat16(f);
  return *(unsigned short*)&h;
}
__device__ __forceinline__ float wredmaxf(float v){
  #pragma unroll
  for (int m=1;m<64;m<<=1) v = fmaxf(v, __shfl_xor(v, m, 64));
  return v;
}
__device__ __forceinline__ float wredsumf(float v){
  #pragma unroll
  for (int m=1;m<64;m<<=1) v += __shfl_xor(v, m, 64);
  return v;
}

// ---------------- kernel 0: fp32 -> bf16 pre-convert (X, qkv_w, proj_w) ----------------
// group sizes (in 8-elem units): X 1181696, Wq 393216, Wp 131072  -> total 1705984 = 6664*256
__global__ __launch_bounds__(256) void cvt_bf16(
    const float* __restrict__ X, const float* __restrict__ Wq, const float* __restrict__ Wp,
    unsigned short* __restrict__ xb, unsigned short* __restrict__ wqb, unsigned short* __restrict__ wpb)
{
  size_t g = (size_t)blockIdx.x*256 + threadIdx.x;
  const float* src; unsigned short* dst; size_t off;
  if (g < 1181696){ src = X; dst = xb; off = g*8; }
  else if (g < 1574912){ src = Wq; dst = wqb; off = (g-1181696)*8; }
  else { src = Wp; dst = wpb; off = (g-1574912)*8; }
  float4 a = *(const float4*)(src+off), b = *(const float4*)(src+off+4);
  unsigned short t[8] = { f2bu(a.x), f2bu(a.y), f2bu(a.z), f2bu(a.w),
                          f2bu(b.x), f2bu(b.y), f2bu(b.z), f2bu(b.w) };
  *(uint4*)(dst+off) = *(uint4*)t;
}

// ---------------- kernel 1: QKV GEMM via MFMA (bf16 inputs pre-converted) ----------------
__global__ __launch_bounds__(256) void gemm_qkv_mfma(
    const unsigned short* __restrict__ Xb, const unsigned short* __restrict__ Wb,
    unsigned short* __restrict__ qb, unsigned short* __restrict__ kb,
    unsigned short* __restrict__ vb)
{
  __shared__ unsigned short As[128][40];
  __shared__ unsigned short Bs[128][40];
  const int tid = threadIdx.x;
  const int lane = tid & 63, wave = tid >> 6;
  const int wm = wave >> 1, wn = wave & 1;
  const int lr = lane & 15, kh = lane >> 4;
  const int bm = blockIdx.x*128, bn = blockIdx.y*128;
  const int srow = tid >> 1, shalf = tid & 1;

  f32x4 acc[4][4];
  #pragma unroll
  for (int i=0;i<4;++i)
    #pragma unroll
    for (int j=0;j<4;++j) acc[i][j] = (f32x4){0.f,0.f,0.f,0.f};

  const int m_s = bm + srow;
  for (int k0=0; k0<1024; k0+=32){
    __syncthreads();
    {
      uint4 a0={0,0,0,0}, a1={0,0,0,0};
      if (m_s < M_){
        const uint4* s = (const uint4*)(Xb + (size_t)m_s*1024 + k0 + shalf*16);
        a0 = s[0]; a1 = s[1];
      }
      *(uint4*)&As[srow][shalf*16]   = a0;
      *(uint4*)&As[srow][shalf*16+8] = a1;
      const uint4* sw = (const uint4*)(Wb + (size_t)(bn+srow)*1024 + k0 + shalf*16);
      *(uint4*)&Bs[srow][shalf*16]   = sw[0];
      *(uint4*)&Bs[srow][shalf*16+8] = sw[1];
    }
    __syncthreads();
    bf16x8 af[4], bfr[4];
    #pragma unroll
    for (int f=0; f<4; ++f){
      af[f]  = *(const bf16x8*)&As[wm*64 + f*16 + lr][kh*8];
      bfr[f] = *(const bf16x8*)&Bs[wn*64 + f*16 + lr][kh*8];
    }
    #pragma unroll
    for (int fm=0; fm<4; ++fm)
      #pragma unroll
      for (int fn=0; fn<4; ++fn)
        acc[fm][fn] = __builtin_amdgcn_mfma_f32_16x16x32_bf16(af[fm], bfr[fn], acc[fm][fn], 0,0,0);
  }
  #pragma unroll
  for (int fm=0; fm<4; ++fm){
    #pragma unroll
    for (int j=0; j<4; ++j){
      int m = bm + wm*64 + fm*16 + kh*4 + j;
      if (m >= M_) continue;
      int b = m / N_, n = m - b*N_;
      #pragma unroll
      for (int fn=0; fn<4; ++fn){
        int c = bn + wn*64 + fn*16 + lr;
        int three = c >> 10, hh = (c >> 6) & 15, dd = c & 63;
        size_t off = ((size_t)(b*H_ + hh)*N_ + n)*DH_ + dd;
        unsigned short val = f2bu(acc[fm][fn][j]);
        if (three == 0)      qb[off] = val;
        else if (three == 1) kb[off] = val;
        else                 vb[off] = val;
      }
    }
  }
}

// ---------------- kernel 1b: V transpose [bh][n][64] -> [bh][d][VTP] ----------------
__global__ __launch_bounds__(256) void transpose_v(
    const unsigned short* __restrict__ vb, unsigned short* __restrict__ vt)
{
  __shared__ unsigned short tile[64][72];   // row stride 144B (16B-aligned)
  const int t = threadIdx.x;
  const int bh = blockIdx.x / 10, nt = blockIdx.x % 10;
  const int n0 = nt*64;
  {
    int r = t >> 2, c0 = (t & 3) * 16;
    int n = n0 + r;
    uint4 a0={0,0,0,0}, a1={0,0,0,0};
    if (n < N_){
      const uint4* s = (const uint4*)(vb + ((size_t)bh*N_ + n)*DH_ + c0);
      a0 = s[0]; a1 = s[1];
    }
    *(uint4*)&tile[r][c0]   = a0;
    *(uint4*)&tile[r][c0+8] = a1;
  }
  __syncthreads();
  {
    int d = t & 63, j0 = (t >> 6) * 16;
    unsigned short v[16];
    #pragma unroll
    for (int i=0;i<16;++i) v[i] = tile[j0+i][d];
    unsigned short* dst = vt + ((size_t)bh*DH_ + d)*VTP + n0 + j0;
    if (n0 + j0 + 15 <= VTP-1){
      *(uint4*)dst     = *(uint4*)&v[0];
      *(uint4*)(dst+8) = *(uint4*)&v[8];
    } else if (n0 + j0 + 7 <= VTP-1){
      *(uint4*)dst = *(uint4*)&v[0];
    }
  }
}

// ---------------- kernel 2: fused attention (QK + PV via MFMA, 10-bit quantized radix) ----------------
__global__ __launch_bounds__(256,6) void attn_kernel(
    const unsigned short* __restrict__ qw, const unsigned short* __restrict__ kw,
    const unsigned short* __restrict__ vt,
    const float* __restrict__ ucb, const int* __restrict__ counter_p,
    unsigned short* __restrict__ ctx, int* __restrict__ delta)
{
  __shared__ __align__(16) float S[16][SST];       // P (bf16, stride 584) aliases after QK
  __shared__ float expl_s[584];
  __shared__ int   cnt_s[584];
  unsigned short (*pus)[584] = (unsigned short (*)[584])&S[0][0];

  const int tid = threadIdx.x;
  const int lane = tid & 63, wave = tid >> 6;
  const int lr = lane & 15, kh = lane >> 4;
  const int blk = blockIdx.x;
  const int bh = blk / 37, tileq = blk % 37;
  const int h = bh & 15;
  const int row0 = tileq * 16;

  const float logc = logf((float)(*counter_p) + 1.0f);
  for (int k2=tid; k2<N_; k2+=256){
    cnt_s[k2] = 0;
    expl_s[k2] = (k2==0) ? 0.f : sqrtf(logc / (ucb[h*N_ + k2] + 1e-6f));
  }

  // ---- QK^T via MFMA ----
  const unsigned short* qbb = qw + (size_t)bh*N_*DH_;
  const unsigned short* kbb = kw + (size_t)bh*N_*DH_;
  bf16x8 aq0 = {0,0,0,0,0,0,0,0}, aq1 = {0,0,0,0,0,0,0,0};
  {
    int qr = row0 + lr;
    if (qr < N_){
      aq0 = *(const bf16x8*)(qbb + (size_t)qr*DH_ + kh*8);
      aq1 = *(const bf16x8*)(qbb + (size_t)qr*DH_ + 32 + kh*8);
    }
  }

  float acc[4][10];
  #pragma unroll
  for (int r=0;r<4;++r)
    #pragma unroll
    for (int s=0;s<10;++s) acc[r][s]=0.f;

  #pragma unroll
  for (int half=0; half<2; ++half){
    const int t0 = half ? 20 : 0, t1 = half ? 37 : 20, keyoff = half*320;
    for (int tile = t0 + wave; tile < t1; tile += 4){
      int keyr = tile*16 + lr;
      bf16x8 b0 = {0,0,0,0,0,0,0,0}, b1 = {0,0,0,0,0,0,0,0};
      if (keyr < N_){
        b0 = *(const bf16x8*)(kbb + (size_t)keyr*DH_ + kh*8);
        b1 = *(const bf16x8*)(kbb + (size_t)keyr*DH_ + 32 + kh*8);
      }
      f32x4 d = (f32x4){0.f,0.f,0.f,0.f};
      d = __builtin_amdgcn_mfma_f32_16x16x32_bf16(aq0, b0, d, 0,0,0);
      d = __builtin_amdgcn_mfma_f32_16x16x32_bf16(aq1, b1, d, 0,0,0);
      int col = tile*16 - keyoff + lr;
      #pragma unroll
      for (int rg=0; rg<4; ++rg)
        S[kh*4+rg][col] = d[rg];
    }
    __syncthreads();
    #pragma unroll
    for (int s=0; s<5; ++s){
      int sg = half*5 + s;
      int k = sg*64 + lane;
      if (k < N_){
        #pragma unroll
        for (int r=0;r<4;++r) acc[r][sg] = S[wave*4+r][k - keyoff];
      }
    }
    __syncthreads();
  }

  // ---- top-k (10-bit quantized ballot radix) + masked softmax + P store ----
  #pragma unroll
  for (int r=0;r<4;++r){
    const int lrow = wave*4 + r;
    const int n = row0 + lrow;
    const bool rv = (n < N_);
    float sc[10], uv[10]; bool vd[10];
    #pragma unroll
    for (int s=0;s<10;++s) sc[s] = acc[r][s]*0.125f;
    float mx0 = -3.4e38f, mn0 = 3.4e38f;
    #pragma unroll
    for (int s=0;s<10;++s){
      int k = s*64 + lane;
      vd[s] = (k >= 1) && (k < N_);
      uv[s] = sc[s] + (k < N_ ? expl_s[k] : 0.f);
      if (vd[s]){ mx0 = fmaxf(mx0, uv[s]); mn0 = fminf(mn0, uv[s]); }
    }
    const float mx1 = wredmaxf(mx0);
    const float mn1 = -wredmaxf(-mn0);
    const float scale = 1022.f / fmaxf(mx1 - mn1, 1e-30f);
    unsigned uq[10];
    #pragma unroll
    for (int s=0;s<10;++s)
      uq[s] = vd[s] ? (1u + (unsigned)((uv[s]-mn1)*scale)) : 0u;   // [1,1023]

    unsigned T = 0u;
    for (int bit=9; bit>=0; --bit){
      unsigned cand = T | (1u << bit);
      int c = 0;
      #pragma unroll
      for (int s=0;s<10;++s) c += (int)__popcll(__ballot(uq[s] >= cand));
      if (c >= KKEEP) T = cand;
    }
    int cgt = 0;
    #pragma unroll
    for (int s=0;s<10;++s) cgt += (int)__popcll(__ballot(uq[s] > T));
    const int rem = KKEEP - cgt;
    unsigned long long em[10];
    #pragma unroll
    for (int s=0;s<10;++s) em[s] = __ballot(uq[s] == T);
    const unsigned long long below = lane ? (~0ull >> (64 - lane)) : 0ull;
    bool keep[10];
    int pref = 0;
    #pragma unroll
    for (int s=0;s<10;++s){
      int k = s*64 + lane;
      bool kp2 = false;
      if (k == 0) kp2 = true;
      else if (k < N_){
        if (uq[s] > T) kp2 = true;
        else if (uq[s] == T) kp2 = (pref + __popcll(em[s] & below)) < rem;
      }
      keep[s] = kp2;
      pref += __popcll(em[s]);
    }
    float mxs = -3.4e38f;
    #pragma unroll
    for (int s=0;s<10;++s) if (keep[s]) mxs = fmaxf(mxs, sc[s]);
    mxs = wredmaxf(mxs);
    float p[10]; float den = 0.f;
    #pragma unroll
    for (int s=0;s<10;++s){ p[s] = keep[s] ? __expf(sc[s]-mxs) : 0.f; den += p[s]; }
    den = wredsumf(den);
    const float inv = 1.0f/den;
    #pragma unroll
    for (int s=0;s<10;++s){
      int k = s*64 + lane;
      if (k < N_) pus[lrow][k] = f2bu(p[s]*inv);
      if (rv && keep[s]) atomicAdd(&cnt_s[k < N_ ? k : 0], 1);
    }
  }
  __syncthreads();   // PV reads all 16 P rows

  // ---- PV via MFMA: O[16q][64d]; wave handles d-block wave*16 ----
  {
    const int d0 = wave*16;
    const unsigned short* vtb = vt + ((size_t)bh*DH_ + d0 + lr)*VTP;
    f32x4 od = (f32x4){0.f,0.f,0.f,0.f};
    #pragma unroll 3
    for (int kb2=0; kb2<18; ++kb2){
      bf16x8 pa  = *(const bf16x8*)&pus[lr][kb2*32 + kh*8];
      bf16x8 vb8 = *(const bf16x8*)(vtb + kb2*32 + kh*8);
      od = __builtin_amdgcn_mfma_f32_16x16x32_bf16(pa, vb8, od, 0,0,0);
    }
    const float v576 = b2f(vtb[576]);
    #pragma unroll
    for (int rg=0; rg<4; ++rg){
      int q = kh*4 + rg;
      float o = fmaf(b2f(pus[q][576]), v576, od[rg]);
      int n0 = row0 + q;
      if (n0 < N_) ctx[((size_t)bh*N_ + n0)*DH_ + d0 + lr] = f2bu(o);
    }
  }
  __syncthreads();
  for (int k2=tid; k2<N_; k2+=256){
    int c2 = cnt_s[k2];
    if (c2) atomicAdd(&delta[h*N_ + k2], c2);
  }
}

// ---------------- kernel 3: output projection via MFMA -> FP32 out ----------------
__global__ __launch_bounds__(256) void gemm_proj_mfma(
    const unsigned short* __restrict__ ctxp, const unsigned short* __restrict__ Wb,
    const float* __restrict__ bias, float* __restrict__ out)
{
  __shared__ unsigned short As[128][40];
  __shared__ unsigned short Bs[128][40];
  const int tid = threadIdx.x;
  const int lane = tid & 63, wave = tid >> 6;
  const int wm = wave >> 1, wn = wave & 1;
  const int lr = lane & 15, kh = lane >> 4;
  const int bm = blockIdx.x*128, bn = blockIdx.y*128;
  const int srow = tid >> 1, shalf = tid & 1;

  f32x4 acc[4][4];
  #pragma unroll
  for (int i=0;i<4;++i)
    #pragma unroll
    for (int j=0;j<4;++j) acc[i][j] = (f32x4){0.f,0.f,0.f,0.f};

  const int m_s = bm + srow;
  const int bb = m_s / N_, nn = m_s - bb*N_;

  for (int k0=0; k0<1024; k0+=32){
    __syncthreads();
    {
      uint4 a0 = {0,0,0,0}, a1 = {0,0,0,0};
      if (m_s < M_){
        int hh = k0 >> 6, dd = (k0 & 63) + shalf*16;
        const uint4* s = (const uint4*)(ctxp + ((size_t)(bb*H_ + hh)*N_ + nn)*DH_ + dd);
        a0 = s[0]; a1 = s[1];
      }
      *(uint4*)&As[srow][shalf*16]   = a0;
      *(uint4*)&As[srow][shalf*16+8] = a1;
      const uint4* sw = (const uint4*)(Wb + (size_t)(bn+srow)*1024 + k0 + shalf*16);
      *(uint4*)&Bs[srow][shalf*16]   = sw[0];
      *(uint4*)&Bs[srow][shalf*16+8] = sw[1];
    }
    __syncthreads();
    bf16x8 af[4], bfr[4];
    #pragma unroll
    for (int f=0; f<4; ++f){
      af[f]  = *(const bf16x8*)&As[wm*64 + f*16 + lr][kh*8];
      bfr[f] = *(const bf16x8*)&Bs[wn*64 + f*16 + lr][kh*8];
    }
    #pragma unroll
    for (int fm=0; fm<4; ++fm)
      #pragma unroll
      for (int fn=0; fn<4; ++fn)
        acc[fm][fn] = __builtin_amdgcn_mfma_f32_16x16x32_bf16(af[fm], bfr[fn], acc[fm][fn], 0,0,0);
  }
  float bv[4];
  #pragma unroll
  for (int fn=0; fn<4; ++fn) bv[fn] = bias[bn + wn*64 + fn*16 + lr];
  #pragma unroll
  for (int fm=0; fm<4; ++fm){
    #pragma unroll
    for (int j=0; j<4; ++j){
      int m = bm + wm*64 + fm*16 + kh*4 + j;
      if (m >= M_) continue;
      #pragma unroll
      for (int fn=0; fn<4; ++fn){
        int c = bn + wn*64 + fn*16 + lr;
        out[(size_t)m*1024 + c] = acc[fm][fn][j] + bv[fn];
      }
    }
  }
}

// ---------------- kernel 4: score_delta int -> FP32 tail of d_out ----------------
__global__ void delta_to_f32(const int* __restrict__ delta, float* __restrict__ outd){
  int i = blockIdx.x*256 + threadIdx.x;
  if (i < H_*N_) outd[i] = (float)delta[i];
}

extern "C" void kernel_launch(void* const* d_in, const int* in_sizes, int n_in,
                              void* d_out, int out_size, void* d_ws, size_t ws_size,
                              hipStream_t stream) {
  const float* x      = (const float*)d_in[0];
  const float* qkv_w  = (const float*)d_in[1];
  const float* proj_w = (const float*)d_in[2];
  const float* proj_b = (const float*)d_in[3];
  const float* ucb    = (const float*)d_in[4];
  const int*   counter= (const int*)d_in[5];

  float* outO = (float*)d_out;
  float* outD = outO + ((size_t)out_size - (size_t)H_*N_);

  // ws layout (~103 MB; ws_size >= 152 MB proven by round-1 behavior)
  unsigned short* xb  = (unsigned short*)d_ws;        // M*C
  unsigned short* wqb = xb  + (size_t)M_*C_;          // 3*C*C
  unsigned short* wpb = wqb + (size_t)3*C_*C_;        // C*C
  unsigned short* qb  = wpb + (size_t)C_*C_;          // M*C (doubles as ctx)
  unsigned short* kb  = qb  + (size_t)M_*C_;
  unsigned short* vb  = kb  + (size_t)M_*C_;
  unsigned short* vt  = vb  + (size_t)M_*C_;          // 256*64*VTP
  int*         delta  = (int*)(vt + (size_t)B_*H_*DH_*VTP);

  hipMemsetAsync(delta, 0, (size_t)H_*N_*sizeof(int), stream);
  cvt_bf16<<<dim3(6664), 256, 0, stream>>>(x, qkv_w, proj_w, xb, wqb, wpb);
  gemm_qkv_mfma<<<dim3(73,24), 256, 0, stream>>>(xb, wqb, qb, kb, vb);
  transpose_v<<<dim3(2560), 256, 0, stream>>>(vb, vt);
  attn_kernel<<<dim3(256*37), 256, 0, stream>>>(qb, kb, vt, ucb, counter, qb /*ctx alias*/, delta);
  gemm_proj_mfma<<<dim3(73,8), 256, 0, stream>>>(qb, wpb, proj_b, outO);
  delta_to_f32<<<dim3(37), 256, 0, stream>>>(delta, outD);
}

// Round 12
// 364.021 us; speedup vs baseline: 9.7369x; 1.0386x over previous
//
#include <hip/hip_runtime.h>
#include <hip/hip_bf16.h>

#define B_ 16
#define N_ 577
#define C_ 1024
#define H_ 16
#define DH_ 64
#define M_ (B_*N_)          // 9232
#define KKEEP 144           // int(576 * 0.25)
#define VTP 584             // padded n-stride of transposed V
#define SST 325             // S row stride (dwords)

typedef __attribute__((ext_vector_type(8))) short bf16x8;
typedef __attribute__((ext_vector_type(4))) float f32x4;

// ---------------- helpers ----------------
__device__ __forceinline__ float b2f(unsigned short u){ return __uint_as_float(((unsigned int)u) << 16); }
__device__ __forceinline__ unsigned short f2bu(float f){
  __hip_bfloat16 h = __float2bfloat16(f);
  return *(unsigned short*)&h;
}
__device__ __forceinline__ float wredmaxf(float v){
  #pragma unroll
  for (int m=1;m<64;m<<=1) v = fmaxf(v, __shfl_xor(v, m, 64));
  return v;
}
__device__ __forceinline__ float wredsumf(float v){
  #pragma unroll
  for (int m=1;m<64;m<<=1) v += __shfl_xor(v, m, 64);
  return v;
}
// async global->LDS, 16B per lane; dest = uniform base + lane*16 (m104)
__device__ __forceinline__ void gload16(const unsigned short* g, unsigned short* l){
  __builtin_amdgcn_global_load_lds(
      (const __attribute__((address_space(1))) unsigned int*)g,
      (__attribute__((address_space(3))) unsigned int*)l,
      16, 0, 0);
}

// ---------------- kernel 0: fp32 -> bf16 pre-convert (X, qkv_w, proj_w) ----------------
__global__ __launch_bounds__(256) void cvt_bf16(
    const float* __restrict__ X, const float* __restrict__ Wq, const float* __restrict__ Wp,
    unsigned short* __restrict__ xb, unsigned short* __restrict__ wqb, unsigned short* __restrict__ wpb)
{
  size_t g = (size_t)blockIdx.x*256 + threadIdx.x;
  const float* src; unsigned short* dst; size_t off;
  if (g < 1181696){ src = X; dst = xb; off = g*8; }
  else if (g < 1574912){ src = Wq; dst = wqb; off = (g-1181696)*8; }
  else { src = Wp; dst = wpb; off = (g-1574912)*8; }
  float4 a = *(const float4*)(src+off), b = *(const float4*)(src+off+4);
  unsigned short t[8] = { f2bu(a.x), f2bu(a.y), f2bu(a.z), f2bu(a.w),
                          f2bu(b.x), f2bu(b.y), f2bu(b.z), f2bu(b.w) };
  *(uint4*)(dst+off) = *(uint4*)t;
}

// ---------------- kernel 1: QKV GEMM via MFMA + global_load_lds staging ----------------
__global__ __launch_bounds__(256) void gemm_qkv_mfma(
    const unsigned short* __restrict__ Xb, const unsigned short* __restrict__ Wb,
    unsigned short* __restrict__ qb, unsigned short* __restrict__ kb,
    unsigned short* __restrict__ vb)
{
  __shared__ __align__(16) unsigned short As[128][32];   // linear: 64B/row, bank-balanced for b128 frags
  __shared__ __align__(16) unsigned short Bs[128][32];
  const int tid = threadIdx.x;
  const int lane = tid & 63, wave = tid >> 6;
  const int wm = wave >> 1, wn = wave & 1;
  const int lr = lane & 15, kh = lane >> 4;
  const int bm = blockIdx.x*128, bn = blockIdx.y*128;

  // staging geometry: 512 granules (16B) per tile, 2 gload insts per wave per matrix
  const int idx0 = (wave*2+0)*64 + lane;
  const int idx1 = (wave*2+1)*64 + lane;
  const int r0 = idx0 >> 2, c0 = idx0 & 3;
  const int r1 = idx1 >> 2, c1 = idx1 & 3;
  const unsigned short* aS0 = Xb + (size_t)(bm + r0)*1024 + c0*8;   // tail rows read into ws (safe)
  const unsigned short* aS1 = Xb + (size_t)(bm + r1)*1024 + c1*8;
  const unsigned short* bS0 = Wb + (size_t)(bn + r0)*1024 + c0*8;
  const unsigned short* bS1 = Wb + (size_t)(bn + r1)*1024 + c1*8;
  unsigned short* aD0 = &As[0][0] + (wave*2+0)*512;
  unsigned short* aD1 = &As[0][0] + (wave*2+1)*512;
  unsigned short* bD0 = &Bs[0][0] + (wave*2+0)*512;
  unsigned short* bD1 = &Bs[0][0] + (wave*2+1)*512;

  const unsigned short* aR[4]; const unsigned short* bR[4];
  #pragma unroll
  for (int f=0; f<4; ++f){
    aR[f] = &As[wm*64 + f*16 + lr][kh*8];
    bR[f] = &Bs[wn*64 + f*16 + lr][kh*8];
  }

  f32x4 acc[4][4];
  #pragma unroll
  for (int i=0;i<4;++i)
    #pragma unroll
    for (int j=0;j<4;++j) acc[i][j] = (f32x4){0.f,0.f,0.f,0.f};

  for (int k0=0; k0<1024; k0+=32){
    __syncthreads();
    gload16(aS0 + k0, aD0);
    gload16(aS1 + k0, aD1);
    gload16(bS0 + k0, bD0);
    gload16(bS1 + k0, bD1);
    __syncthreads();
    bf16x8 af[4], bfr[4];
    #pragma unroll
    for (int f=0; f<4; ++f){
      af[f]  = *(const bf16x8*)aR[f];
      bfr[f] = *(const bf16x8*)bR[f];
    }
    #pragma unroll
    for (int fm=0; fm<4; ++fm)
      #pragma unroll
      for (int fn=0; fn<4; ++fn)
        acc[fm][fn] = __builtin_amdgcn_mfma_f32_16x16x32_bf16(af[fm], bfr[fn], acc[fm][fn], 0,0,0);
  }
  #pragma unroll
  for (int fm=0; fm<4; ++fm){
    #pragma unroll
    for (int j=0; j<4; ++j){
      int m = bm + wm*64 + fm*16 + kh*4 + j;
      if (m >= M_) continue;
      int b = m / N_, n = m - b*N_;
      #pragma unroll
      for (int fn=0; fn<4; ++fn){
        int c = bn + wn*64 + fn*16 + lr;
        int three = c >> 10, hh = (c >> 6) & 15, dd = c & 63;
        size_t off = ((size_t)(b*H_ + hh)*N_ + n)*DH_ + dd;
        unsigned short val = f2bu(acc[fm][fn][j]);
        if (three == 0)      qb[off] = val;
        else if (three == 1) kb[off] = val;
        else                 vb[off] = val;
      }
    }
  }
}

// ---------------- kernel 1b: V transpose [bh][n][64] -> [bh][d][VTP] ----------------
__global__ __launch_bounds__(256) void transpose_v(
    const unsigned short* __restrict__ vb, unsigned short* __restrict__ vt)
{
  __shared__ unsigned short tile[64][72];
  const int t = threadIdx.x;
  const int bh = blockIdx.x / 10, nt = blockIdx.x % 10;
  const int n0 = nt*64;
  {
    int r = t >> 2, c0 = (t & 3) * 16;
    int n = n0 + r;
    uint4 a0={0,0,0,0}, a1={0,0,0,0};
    if (n < N_){
      const uint4* s = (const uint4*)(vb + ((size_t)bh*N_ + n)*DH_ + c0);
      a0 = s[0]; a1 = s[1];
    }
    *(uint4*)&tile[r][c0]   = a0;
    *(uint4*)&tile[r][c0+8] = a1;
  }
  __syncthreads();
  {
    int d = t & 63, j0 = (t >> 6) * 16;
    unsigned short v[16];
    #pragma unroll
    for (int i=0;i<16;++i) v[i] = tile[j0+i][d];
    unsigned short* dst = vt + ((size_t)bh*DH_ + d)*VTP + n0 + j0;
    if (n0 + j0 + 15 <= VTP-1){
      *(uint4*)dst     = *(uint4*)&v[0];
      *(uint4*)(dst+8) = *(uint4*)&v[8];
    } else if (n0 + j0 + 7 <= VTP-1){
      *(uint4*)dst = *(uint4*)&v[0];
    }
  }
}

// ---------------- kernel 2: fused attention (UNCHANGED from round 11) ----------------
__global__ __launch_bounds__(256,6) void attn_kernel(
    const unsigned short* __restrict__ qw, const unsigned short* __restrict__ kw,
    const unsigned short* __restrict__ vt,
    const float* __restrict__ ucb, const int* __restrict__ counter_p,
    unsigned short* __restrict__ ctx, int* __restrict__ delta)
{
  __shared__ __align__(16) float S[16][SST];
  __shared__ float expl_s[584];
  __shared__ int   cnt_s[584];
  unsigned short (*pus)[584] = (unsigned short (*)[584])&S[0][0];

  const int tid = threadIdx.x;
  const int lane = tid & 63, wave = tid >> 6;
  const int lr = lane & 15, kh = lane >> 4;
  const int blk = blockIdx.x;
  const int bh = blk / 37, tileq = blk % 37;
  const int h = bh & 15;
  const int row0 = tileq * 16;

  const float logc = logf((float)(*counter_p) + 1.0f);
  for (int k2=tid; k2<N_; k2+=256){
    cnt_s[k2] = 0;
    expl_s[k2] = (k2==0) ? 0.f : sqrtf(logc / (ucb[h*N_ + k2] + 1e-6f));
  }

  const unsigned short* qbb = qw + (size_t)bh*N_*DH_;
  const unsigned short* kbb = kw + (size_t)bh*N_*DH_;
  bf16x8 aq0 = {0,0,0,0,0,0,0,0}, aq1 = {0,0,0,0,0,0,0,0};
  {
    int qr = row0 + lr;
    if (qr < N_){
      aq0 = *(const bf16x8*)(qbb + (size_t)qr*DH_ + kh*8);
      aq1 = *(const bf16x8*)(qbb + (size_t)qr*DH_ + 32 + kh*8);
    }
  }

  float acc[4][10];
  #pragma unroll
  for (int r=0;r<4;++r)
    #pragma unroll
    for (int s=0;s<10;++s) acc[r][s]=0.f;

  #pragma unroll
  for (int half=0; half<2; ++half){
    const int t0 = half ? 20 : 0, t1 = half ? 37 : 20, keyoff = half*320;
    for (int tile = t0 + wave; tile < t1; tile += 4){
      int keyr = tile*16 + lr;
      bf16x8 b0 = {0,0,0,0,0,0,0,0}, b1 = {0,0,0,0,0,0,0,0};
      if (keyr < N_){
        b0 = *(const bf16x8*)(kbb + (size_t)keyr*DH_ + kh*8);
        b1 = *(const bf16x8*)(kbb + (size_t)keyr*DH_ + 32 + kh*8);
      }
      f32x4 d = (f32x4){0.f,0.f,0.f,0.f};
      d = __builtin_amdgcn_mfma_f32_16x16x32_bf16(aq0, b0, d, 0,0,0);
      d = __builtin_amdgcn_mfma_f32_16x16x32_bf16(aq1, b1, d, 0,0,0);
      int col = tile*16 - keyoff + lr;
      #pragma unroll
      for (int rg=0; rg<4; ++rg)
        S[kh*4+rg][col] = d[rg];
    }
    __syncthreads();
    #pragma unroll
    for (int s=0; s<5; ++s){
      int sg = half*5 + s;
      int k = sg*64 + lane;
      if (k < N_){
        #pragma unroll
        for (int r=0;r<4;++r) acc[r][sg] = S[wave*4+r][k - keyoff];
      }
    }
    __syncthreads();
  }

  #pragma unroll
  for (int r=0;r<4;++r){
    const int lrow = wave*4 + r;
    const int n = row0 + lrow;
    const bool rv = (n < N_);
    float sc[10], uv[10]; bool vd[10];
    #pragma unroll
    for (int s=0;s<10;++s) sc[s] = acc[r][s]*0.125f;
    float mx0 = -3.4e38f, mn0 = 3.4e38f;
    #pragma unroll
    for (int s=0;s<10;++s){
      int k = s*64 + lane;
      vd[s] = (k >= 1) && (k < N_);
      uv[s] = sc[s] + (k < N_ ? expl_s[k] : 0.f);
      if (vd[s]){ mx0 = fmaxf(mx0, uv[s]); mn0 = fminf(mn0, uv[s]); }
    }
    const float mx1 = wredmaxf(mx0);
    const float mn1 = -wredmaxf(-mn0);
    const float scale = 1022.f / fmaxf(mx1 - mn1, 1e-30f);
    unsigned uq[10];
    #pragma unroll
    for (int s=0;s<10;++s)
      uq[s] = vd[s] ? (1u + (unsigned)((uv[s]-mn1)*scale)) : 0u;

    unsigned T = 0u;
    for (int bit=9; bit>=0; --bit){
      unsigned cand = T | (1u << bit);
      int c = 0;
      #pragma unroll
      for (int s=0;s<10;++s) c += (int)__popcll(__ballot(uq[s] >= cand));
      if (c >= KKEEP) T = cand;
    }
    int cgt = 0;
    #pragma unroll
    for (int s=0;s<10;++s) cgt += (int)__popcll(__ballot(uq[s] > T));
    const int rem = KKEEP - cgt;
    unsigned long long em[10];
    #pragma unroll
    for (int s=0;s<10;++s) em[s] = __ballot(uq[s] == T);
    const unsigned long long below = lane ? (~0ull >> (64 - lane)) : 0ull;
    bool keep[10];
    int pref = 0;
    #pragma unroll
    for (int s=0;s<10;++s){
      int k = s*64 + lane;
      bool kp2 = false;
      if (k == 0) kp2 = true;
      else if (k < N_){
        if (uq[s] > T) kp2 = true;
        else if (uq[s] == T) kp2 = (pref + __popcll(em[s] & below)) < rem;
      }
      keep[s] = kp2;
      pref += __popcll(em[s]);
    }
    float mxs = -3.4e38f;
    #pragma unroll
    for (int s=0;s<10;++s) if (keep[s]) mxs = fmaxf(mxs, sc[s]);
    mxs = wredmaxf(mxs);
    float p[10]; float den = 0.f;
    #pragma unroll
    for (int s=0;s<10;++s){ p[s] = keep[s] ? __expf(sc[s]-mxs) : 0.f; den += p[s]; }
    den = wredsumf(den);
    const float inv = 1.0f/den;
    #pragma unroll
    for (int s=0;s<10;++s){
      int k = s*64 + lane;
      if (k < N_) pus[lrow][k] = f2bu(p[s]*inv);
      if (rv && keep[s]) atomicAdd(&cnt_s[k < N_ ? k : 0], 1);
    }
  }
  __syncthreads();

  {
    const int d0 = wave*16;
    const unsigned short* vtb = vt + ((size_t)bh*DH_ + d0 + lr)*VTP;
    f32x4 od = (f32x4){0.f,0.f,0.f,0.f};
    #pragma unroll 3
    for (int kb2=0; kb2<18; ++kb2){
      bf16x8 pa  = *(const bf16x8*)&pus[lr][kb2*32 + kh*8];
      bf16x8 vb8 = *(const bf16x8*)(vtb + kb2*32 + kh*8);
      od = __builtin_amdgcn_mfma_f32_16x16x32_bf16(pa, vb8, od, 0,0,0);
    }
    const float v576 = b2f(vtb[576]);
    #pragma unroll
    for (int rg=0; rg<4; ++rg){
      int q = kh*4 + rg;
      float o = fmaf(b2f(pus[q][576]), v576, od[rg]);
      int n0 = row0 + q;
      if (n0 < N_) ctx[((size_t)bh*N_ + n0)*DH_ + d0 + lr] = f2bu(o);
    }
  }
  __syncthreads();
  for (int k2=tid; k2<N_; k2+=256){
    int c2 = cnt_s[k2];
    if (c2) atomicAdd(&delta[h*N_ + k2], c2);
  }
}

// ---------------- kernel 3: output projection via MFMA + global_load_lds ----------------
__global__ __launch_bounds__(256) void gemm_proj_mfma(
    const unsigned short* __restrict__ ctxp, const unsigned short* __restrict__ Wb,
    const float* __restrict__ bias, float* __restrict__ out)
{
  __shared__ __align__(16) unsigned short As[128][32];
  __shared__ __align__(16) unsigned short Bs[128][32];
  const int tid = threadIdx.x;
  const int lane = tid & 63, wave = tid >> 6;
  const int wm = wave >> 1, wn = wave & 1;
  const int lr = lane & 15, kh = lane >> 4;
  const int bm = blockIdx.x*128, bn = blockIdx.y*128;

  const int idx0 = (wave*2+0)*64 + lane;
  const int idx1 = (wave*2+1)*64 + lane;
  const int r0 = idx0 >> 2, c0 = idx0 & 3;
  const int r1 = idx1 >> 2, c1 = idx1 & 3;
  // A source: gather from ctx [bh][n][64]; logical col kg = k0 + c*8 -> hh=kg>>6, dd=kg&63
  const int m0r = bm + r0, m1r = bm + r1;
  const int b0 = m0r / N_, n0r = m0r - b0*N_;
  const int b1 = m1r / N_, n1r = m1r - b1*N_;
  const unsigned short* aBase0 = ctxp + ((size_t)b0*H_*N_ + n0r)*DH_ + c0*8;
  const unsigned short* aBase1 = ctxp + ((size_t)b1*H_*N_ + n1r)*DH_ + c1*8;
  const unsigned short* bS0 = Wb + (size_t)(bn + r0)*1024 + c0*8;
  const unsigned short* bS1 = Wb + (size_t)(bn + r1)*1024 + c1*8;
  unsigned short* aD0 = &As[0][0] + (wave*2+0)*512;
  unsigned short* aD1 = &As[0][0] + (wave*2+1)*512;
  unsigned short* bD0 = &Bs[0][0] + (wave*2+0)*512;
  unsigned short* bD1 = &Bs[0][0] + (wave*2+1)*512;

  const unsigned short* aR[4]; const unsigned short* bR[4];
  #pragma unroll
  for (int f=0; f<4; ++f){
    aR[f] = &As[wm*64 + f*16 + lr][kh*8];
    bR[f] = &Bs[wn*64 + f*16 + lr][kh*8];
  }

  f32x4 acc[4][4];
  #pragma unroll
  for (int i=0;i<4;++i)
    #pragma unroll
    for (int j=0;j<4;++j) acc[i][j] = (f32x4){0.f,0.f,0.f,0.f};

  for (int k0=0; k0<1024; k0+=32){
    __syncthreads();
    const size_t hoff = (size_t)(k0 >> 6)*(N_*DH_) + (k0 & 63);
    gload16(aBase0 + hoff, aD0);
    gload16(aBase1 + hoff, aD1);
    gload16(bS0 + k0, bD0);
    gload16(bS1 + k0, bD1);
    __syncthreads();
    bf16x8 af[4], bfr[4];
    #pragma unroll
    for (int f=0; f<4; ++f){
      af[f]  = *(const bf16x8*)aR[f];
      bfr[f] = *(const bf16x8*)bR[f];
    }
    #pragma unroll
    for (int fm=0; fm<4; ++fm)
      #pragma unroll
      for (int fn=0; fn<4; ++fn)
        acc[fm][fn] = __builtin_amdgcn_mfma_f32_16x16x32_bf16(af[fm], bfr[fn], acc[fm][fn], 0,0,0);
  }
  float bv[4];
  #pragma unroll
  for (int fn=0; fn<4; ++fn) bv[fn] = bias[bn + wn*64 + fn*16 + lr];
  #pragma unroll
  for (int fm=0; fm<4; ++fm){
    #pragma unroll
    for (int j=0; j<4; ++j){
      int m = bm + wm*64 + fm*16 + kh*4 + j;
      if (m >= M_) continue;
      #pragma unroll
      for (int fn=0; fn<4; ++fn){
        int c = bn + wn*64 + fn*16 + lr;
        out[(size_t)m*1024 + c] = acc[fm][fn][j] + bv[fn];
      }
    }
  }
}

// ---------------- kernel 4: score_delta int -> FP32 tail of d_out ----------------
__global__ void delta_to_f32(const int* __restrict__ delta, float* __restrict__ outd){
  int i = blockIdx.x*256 + threadIdx.x;
  if (i < H_*N_) outd[i] = (float)delta[i];
}

extern "C" void kernel_launch(void* const* d_in, const int* in_sizes, int n_in,
                              void* d_out, int out_size, void* d_ws, size_t ws_size,
                              hipStream_t stream) {
  const float* x      = (const float*)d_in[0];
  const float* qkv_w  = (const float*)d_in[1];
  const float* proj_w = (const float*)d_in[2];
  const float* proj_b = (const float*)d_in[3];
  const float* ucb    = (const float*)d_in[4];
  const int*   counter= (const int*)d_in[5];

  float* outO = (float*)d_out;
  float* outD = outO + ((size_t)out_size - (size_t)H_*N_);

  unsigned short* xb  = (unsigned short*)d_ws;        // M*C
  unsigned short* wqb = xb  + (size_t)M_*C_;          // 3*C*C
  unsigned short* wpb = wqb + (size_t)3*C_*C_;        // C*C
  unsigned short* qb  = wpb + (size_t)C_*C_;          // M*C (doubles as ctx)
  unsigned short* kb  = qb  + (size_t)M_*C_;
  unsigned short* vb  = kb  + (size_t)M_*C_;
  unsigned short* vt  = vb  + (size_t)M_*C_;          // 256*64*VTP
  int*         delta  = (int*)(vt + (size_t)B_*H_*DH_*VTP);

  hipMemsetAsync(delta, 0, (size_t)H_*N_*sizeof(int), stream);
  cvt_bf16<<<dim3(6664), 256, 0, stream>>>(x, qkv_w, proj_w, xb, wqb, wpb);
  gemm_qkv_mfma<<<dim3(73,24), 256, 0, stream>>>(xb, wqb, qb, kb, vb);
  transpose_v<<<dim3(2560), 256, 0, stream>>>(vb, vt);
  attn_kernel<<<dim3(256*37), 256, 0, stream>>>(qb, kb, vt, ucb, counter, qb /*ctx alias*/, delta);
  gemm_proj_mfma<<<dim3(73,8), 256, 0, stream>>>(qb, wpb, proj_b, outO);
  delta_to_f32<<<dim3(37), 256, 0, stream>>>(delta, outD);
}